// Round 3
// baseline (663.774 us; speedup 1.0000x reference)
//
#include <hip/hip_runtime.h>
#include <hip/hip_bf16.h>
#include <cmath>

#define CDIM 256
#define TPW 49
#define NWIN 1024
#define MTOK (NWIN * TPW)   // 50176 tokens (windowed order)
#define NHEAD 8
#define GH 224
#define GW 56
#define PLD 72              // padded LDS row (bf16 elems)

typedef __attribute__((ext_vector_type(8))) __bf16 bf16x8;
typedef __attribute__((ext_vector_type(4))) float f32x4;

__device__ __forceinline__ __bf16 to_bf16(float f) {
    __hip_bfloat16 h = __float2bfloat16(f);
    return *(__bf16*)&h;
}

__device__ __forceinline__ unsigned pack2(float a, float b) {
    __hip_bfloat16 ha = __float2bfloat16(a);
    __hip_bfloat16 hb = __float2bfloat16(b);
    return (unsigned)*(unsigned short*)&ha | ((unsigned)*(unsigned short*)&hb << 16);
}

__device__ __forceinline__ void async_copy16(const void* g, void* l) {
    __builtin_amdgcn_global_load_lds(
        (const __attribute__((address_space(1))) void*)g,
        (__attribute__((address_space(3))) void*)l, 16, 0, 0);
}

__device__ __forceinline__ float wave_sum(float v) {
    v += __shfl_down(v, 32);
    v += __shfl_down(v, 16);
    v += __shfl_down(v, 8);
    v += __shfl_down(v, 4);
    v += __shfl_down(v, 2);
    v += __shfl_down(v, 1);
    return v;
}

// all four weight tensors -> bf16, one launch
__global__ __launch_bounds__(256) void castall_kernel(
    const float* __restrict__ qw, const float* __restrict__ pw,
    const float* __restrict__ f1, const float* __restrict__ f2,
    __hip_bfloat16* __restrict__ dst)
{
    const int i = blockIdx.x * 256 + threadIdx.x;
    float v;
    if (i < 196608) v = qw[i];
    else if (i < 262144) v = pw[i - 196608];
    else if (i < 524288) v = f1[i - 262144];
    else v = f2[i - 524288];
    dst[i] = __float2bfloat16(v);
}

// Combined rel-pos bias + shift mask, transposed: cbt[cls*8+head][m][n] (64x64).
__global__ __launch_bounds__(256) void cb_kernel(
    const float* __restrict__ rpb, float* __restrict__ cbt)
{
    const int cls = blockIdx.x >> 3, head = blockIdx.x & 7;
    for (int e = threadIdx.x; e < 64 * 64; e += 256) {
        const int m = e >> 6, n = e & 63;
        float v;
        if (m >= 49 || n >= 49) v = -30000.0f;
        else {
            const int in_ = n / 7, jn = n - in_ * 7;
            const int im = m / 7, jm = m - im * 7;
            v = rpb[((in_ - im + 6) * 13 + (jn - jm + 6)) * 8 + head];
            const int hn = (cls & 2) ? 217 + in_ : in_;
            const int wn = (cls & 1) ? 49 + jn : jn;
            const int hm = (cls & 2) ? 217 + im : im;
            const int wm = (cls & 1) ? 49 + jm : jm;
            const int rn = (hn < 217 ? 0 : (hn < 221 ? 3 : 6)) + (wn < 49 ? 0 : (wn < 53 ? 1 : 2));
            const int rm = (hm < 217 ? 0 : (hm < 221 ? 3 : 6)) + (wm < 49 ? 0 : (wm < 53 ? 1 : 2));
            if (rn != rm) v -= 100.0f;
        }
        cbt[((long)blockIdx.x * 64 + m) * 64 + n] = v;
    }
}

// LN over C=256 fused with roll(-3,-3) + 7x7 window partition gather -> bf16.
// One WAVE per token (4 tokens/block).
__global__ __launch_bounds__(256) void ln1_window_kernel(
    const float* __restrict__ x1, const float* __restrict__ g,
    const float* __restrict__ b, __hip_bfloat16* __restrict__ out)
{
    const int wave = threadIdx.x >> 6, lane = threadIdx.x & 63;
    const int t = blockIdx.x * 4 + wave;
    const int bw = t / TPW, n = t - bw * TPW;
    const int bb = bw >> 8, wi = bw & 255;
    const int hb = wi >> 3, wb = wi & 7;
    const int i = n / 7, j = n - i * 7;
    int h0 = hb * 7 + i + 3; if (h0 >= GH) h0 -= GH;
    int w0 = wb * 7 + j + 3; if (w0 >= GW) w0 -= GW;
    const long src = ((long)(bb * GH + h0) * GW + w0) * CDIM + lane * 4;
    const float4 v = *(const float4*)(x1 + src);
    float s = v.x + v.y + v.z + v.w;
    s = wave_sum(s);
    const float mean = __shfl(s, 0) * (1.0f / 256.0f);
    const float4 d = { v.x - mean, v.y - mean, v.z - mean, v.w - mean };
    float s2 = d.x * d.x + d.y * d.y + d.z * d.z + d.w * d.w;
    s2 = wave_sum(s2);
    const float rstd = rsqrtf(__shfl(s2, 0) * (1.0f / 256.0f) + 1e-5f);
    const float4 g4 = *(const float4*)(g + lane * 4);
    const float4 b4 = *(const float4*)(b + lane * 4);
    short4 pk;
    { __bf16 h = to_bf16(d.x * rstd * g4.x + b4.x); pk.x = *(short*)&h; }
    { __bf16 h = to_bf16(d.y * rstd * g4.y + b4.y); pk.y = *(short*)&h; }
    { __bf16 h = to_bf16(d.z * rstd * g4.z + b4.z); pk.z = *(short*)&h; }
    { __bf16 h = to_bf16(d.w * rstd * g4.w + b4.w); pk.w = *(short*)&h; }
    *(short4*)((short*)out + (long)t * CDIM + lane * 4) = pk;
}

// Plain LN over C=256 -> bf16. One WAVE per token (4 tokens/block).
__global__ __launch_bounds__(256) void ln_kernel(
    const float* __restrict__ x, const float* __restrict__ g,
    const float* __restrict__ b, __hip_bfloat16* __restrict__ out)
{
    const int wave = threadIdx.x >> 6, lane = threadIdx.x & 63;
    const long t = (long)blockIdx.x * 4 + wave;
    const float4 v = *(const float4*)(x + t * CDIM + lane * 4);
    float s = v.x + v.y + v.z + v.w;
    s = wave_sum(s);
    const float mean = __shfl(s, 0) * (1.0f / 256.0f);
    const float4 d = { v.x - mean, v.y - mean, v.z - mean, v.w - mean };
    float s2 = d.x * d.x + d.y * d.y + d.z * d.z + d.w * d.w;
    s2 = wave_sum(s2);
    const float rstd = rsqrtf(__shfl(s2, 0) * (1.0f / 256.0f) + 1e-5f);
    const float4 g4 = *(const float4*)(g + lane * 4);
    const float4 b4 = *(const float4*)(b + lane * 4);
    short4 pk;
    { __bf16 h = to_bf16(d.x * rstd * g4.x + b4.x); pk.x = *(short*)&h; }
    { __bf16 h = to_bf16(d.y * rstd * g4.y + b4.y); pk.y = *(short*)&h; }
    { __bf16 h = to_bf16(d.z * rstd * g4.z + b4.z); pk.z = *(short*)&h; }
    { __bf16 h = to_bf16(d.w * rstd * g4.w + b4.w); pk.w = *(short*)&h; }
    *(short4*)((short*)out + t * CDIM + lane * 4) = pk;
}

// MFMA GEMM (unchanged): 128x128 tile, BK=32, 4 waves, XCD swizzle.
// EPI: 0 = bias (bf16 out), 3 = proj+scatter: Y=x1b (fp32), Y2=out_y, res=x1.
template <int EPI, typename OutT>
__global__ __launch_bounds__(256) void gemm_mfma(
    const __hip_bfloat16* __restrict__ X, const __hip_bfloat16* __restrict__ W,
    const float* __restrict__ bias, OutT* __restrict__ Y,
    int M, int K, int N, const float* __restrict__ res, float* __restrict__ Y2)
{
    __shared__ __hip_bfloat16 As[128 * 32];
    __shared__ __hip_bfloat16 Bs[128 * 32];
    const int tid = threadIdx.x;
    const int wave = tid >> 6, lane = tid & 63;
    const int nwg = gridDim.x * gridDim.y;
    const int L = blockIdx.y * gridDim.x + blockIdx.x;
    const int cpx = nwg >> 3;
    const int orig = (L & 7) * cpx + (L >> 3);
    const int bxx = orig % gridDim.x;
    const int byy = orig / gridDim.x;
    const int bm = byy * 128, bn = bxx * 128;
    const int wm = (wave & 1) * 64, wn = (wave >> 1) * 64;
    const int m16 = lane & 15, quad = lane >> 4;
    const int srow = lane >> 2;
    const int scol = (lane & 3) * 8;

    f32x4 acc[4][4] = {};

    for (int k0 = 0; k0 < K; k0 += 32) {
#pragma unroll
        for (int j = 0; j < 2; ++j) {
            const int rg = wave * 2 + j;
            const int row = rg * 16 + srow;
            async_copy16(X + (long)(bm + row) * K + k0 + scol, (char*)As + rg * 1024);
            async_copy16(W + (long)(bn + row) * K + k0 + scol, (char*)Bs + rg * 1024);
        }
        __syncthreads();
        bf16x8 af[4], bf[4];
#pragma unroll
        for (int i = 0; i < 4; ++i)
            af[i] = *(const bf16x8*)&As[(wm + i * 16 + m16) * 32 + quad * 8];
#pragma unroll
        for (int j = 0; j < 4; ++j)
            bf[j] = *(const bf16x8*)&Bs[(wn + j * 16 + m16) * 32 + quad * 8];
#pragma unroll
        for (int i = 0; i < 4; ++i)
#pragma unroll
            for (int j = 0; j < 4; ++j)
                acc[i][j] = __builtin_amdgcn_mfma_f32_16x16x32_bf16(bf[j], af[i], acc[i][j], 0, 0, 0);
        __syncthreads();
    }

#pragma unroll
    for (int i = 0; i < 4; ++i) {
        const long row = bm + wm + i * 16 + m16;
        long drow = row;
        if (EPI == 3) {
            const unsigned t = (unsigned)row;
            const unsigned bw_ = t / 49u;
            const unsigned n_ = t - bw_ * 49u;
            const unsigned bb = bw_ >> 8, wi = bw_ & 255u;
            const unsigned hb = wi >> 3, wbl = wi & 7u;
            const unsigned ii = n_ / 7u, jj = n_ - ii * 7u;
            int h0 = hb * 7 + ii + 3; if (h0 >= GH) h0 -= GH;
            int w0 = wbl * 7 + jj + 3; if (w0 >= GW) w0 -= GW;
            drow = (long)bb * (GH * GW) + h0 * GW + w0;
        }
#pragma unroll
        for (int j = 0; j < 4; ++j) {
            const int col = bn + wn + j * 16 + quad * 4;
            const float4 b4 = *(const float4*)&bias[col];
            float v[4];
            v[0] = acc[i][j][0] + b4.x;
            v[1] = acc[i][j][1] + b4.y;
            v[2] = acc[i][j][2] + b4.z;
            v[3] = acc[i][j][3] + b4.w;
            if (EPI == 1) {
#pragma unroll
                for (int r = 0; r < 4; ++r)
                    v[r] = 0.5f * v[r] * (1.0f + erff(v[r] * 0.70710678118654752f));
            }
            if (EPI == 0 || EPI == 1) {
                short4 pk;
                { __bf16 h = to_bf16(v[0]); pk.x = *(short*)&h; }
                { __bf16 h = to_bf16(v[1]); pk.y = *(short*)&h; }
                { __bf16 h = to_bf16(v[2]); pk.z = *(short*)&h; }
                { __bf16 h = to_bf16(v[3]); pk.w = *(short*)&h; }
                *(short4*)((short*)Y + row * N + col) = pk;
            } else if (EPI == 2) {
                const float4 r4 = *(const float4*)(res + row * N + col);
                float4 o4 = { v[0] + r4.x, v[1] + r4.y, v[2] + r4.z, v[3] + r4.w };
                *(float4*)((float*)Y + row * N + col) = o4;
            } else if (EPI == 3) {
                const long a = drow * 256 + col;
                const float4 x4 = *(const float4*)(res + a);
                float4 y4 = { v[0], v[1], v[2], v[3] };
                *(float4*)(Y2 + a) = y4;
                float4 s4 = { v[0] + x4.x, v[1] + x4.y, v[2] + x4.z, v[3] + x4.w };
                *(float4*)((float*)Y + a) = s4;
            }
        }
    }
}

// Fused MLP v2: io += GELU(A @ W1^T + b1) @ W2^T + b2 (in-place residual).
// 128 rows/block (4 waves x 32 rows), hidden chunks of 64 (16 chunks).
// - A in registers (af[2][8], rows loaded from HBM exactly once)
// - 2 m-frags/wave -> every W fragment read from LDS feeds 2 MFMAs
// - h NEVER touches LDS: GEMM1 output rows are already m16-aligned with
//   GEMM2's B-operand rows; hidden-col regrouping (quad*4 -> quad*8) done
//   with cross-quad shuffles on packed bf16 pairs.
// - W1buf/W2buf single-buffered 32KB each (64KB total) with a 2-barrier
//   rotation: W1[c+1] staged during GEMM2(c), W2[c+1] during GEMM1(c+1),
//   so every __syncthreads vmcnt-drain waits on already-arrived data.
__global__ __launch_bounds__(256, 2) void fused_mlp_kernel(
    const __hip_bfloat16* __restrict__ A,   // MTOK x 256 (ln2 out, bf16)
    const __hip_bfloat16* __restrict__ W1,  // 1024 x 256
    const float* __restrict__ b1,           // 1024
    const __hip_bfloat16* __restrict__ W2,  // 256 x 1024
    const float* __restrict__ b2,           // 256
    float* __restrict__ io)                 // MTOK x 256 fp32, in-place
{
    __shared__ __hip_bfloat16 W1buf[16384]; // 32 KB: 64 hid x 256 K
    __shared__ __hip_bfloat16 W2buf[16384]; // 32 KB: 256 out x 64 K
    const int tid = threadIdx.x;
    const int wave = tid >> 6, lane = tid & 63;
    const int m16 = lane & 15, quad = lane >> 4;
    // XCD swizzle (392 = 8*49 blocks)
    const int L = blockIdx.x;
    const int orig = (L & 7) * 49 + (L >> 3);
    const long bm = (long)orig * 128;

    const int selhi = (lane >> 5) & 1;                 // quad>>1
    const int lA = ((lane & 16) << 1) | (lane & 15);   // src lane (quad 0 or 2)

    // A fragments: wave's 32 rows (2 m-frags), all K=256, in registers
    bf16x8 af[2][8];
#pragma unroll
    for (int m = 0; m < 2; ++m) {
        const __hip_bfloat16* arow = A + (bm + wave * 32 + m * 16 + m16) * 256 + quad * 8;
#pragma unroll
        for (int kk = 0; kk < 8; ++kk)
            af[m][kk] = *(const bf16x8*)(arow + kk * 32);
    }

    // prologue staging: W1[0], W2[0]
    {
        const __hip_bfloat16* src = W1;
#pragma unroll
        for (int r = 0; r < 8; ++r) {
            const int s = (tid << 4) + (r << 12);
            const int row = s >> 9;
            const int g = ((s >> 4) & 31) ^ (row & 7);
            async_copy16(src + row * 256 + g * 8, (char*)W1buf + (r << 12) + wave * 1024);
        }
        const __hip_bfloat16* src2 = W2;
#pragma unroll
        for (int r = 0; r < 8; ++r) {
            const int s = (tid << 4) + (r << 12);
            const int row = s >> 7;
            const int g = ((s >> 4) & 7) ^ (row & 7);
            async_copy16(src2 + (long)row * 1024 + g * 8, (char*)W2buf + (r << 12) + wave * 1024);
        }
    }
    __syncthreads();

    f32x4 acc2[2][16] = {};

    for (int c = 0; c < 16; ++c) {
        // ---- GEMM1(c): s1[m][j], K=256 from registers, W1 from LDS (reuse 2)
        f32x4 s1[2][4] = {};
#pragma unroll
        for (int kk = 0; kk < 8; ++kk) {
#pragma unroll
            for (int j = 0; j < 4; ++j) {
                const int n = j * 16 + m16;
                const int off = n * 512 + ((kk * 64 + quad * 16) ^ ((n & 7) << 4));
                const bf16x8 wf = *(const bf16x8*)((const char*)W1buf + off);
                s1[0][j] = __builtin_amdgcn_mfma_f32_16x16x32_bf16(wf, af[0][kk], s1[0][j], 0, 0, 0);
                s1[1][j] = __builtin_amdgcn_mfma_f32_16x16x32_bf16(wf, af[1][kk], s1[1][j], 0, 0, 0);
            }
        }
        // ---- bias + GELU + pack to bf16 pairs (register only)
        unsigned pkl[2][4], pkh[2][4];
#pragma unroll
        for (int m = 0; m < 2; ++m)
#pragma unroll
            for (int j = 0; j < 4; ++j) {
                const float4 bb = *(const float4*)(b1 + c * 64 + j * 16 + quad * 4);
                float v[4];
                v[0] = s1[m][j][0] + bb.x; v[1] = s1[m][j][1] + bb.y;
                v[2] = s1[m][j][2] + bb.z; v[3] = s1[m][j][3] + bb.w;
#pragma unroll
                for (int r = 0; r < 4; ++r)
                    v[r] = 0.5f * v[r] * (1.0f + erff(v[r] * 0.70710678118654752f));
                pkl[m][j] = pack2(v[0], v[1]);
                pkh[m][j] = pack2(v[2], v[3]);
            }
        __syncthreads();   // all W1buf reads done (drains W2[c], overlapped)
        // ---- stage W1[c+1] (in flight during GEMM2)
        if (c < 15) {
            const __hip_bfloat16* src = W1 + (long)(c + 1) * 64 * 256;
#pragma unroll
            for (int r = 0; r < 8; ++r) {
                const int s = (tid << 4) + (r << 12);
                const int row = s >> 9;
                const int g = ((s >> 4) & 31) ^ (row & 7);
                async_copy16(src + row * 256 + g * 8, (char*)W1buf + (r << 12) + wave * 1024);
            }
        }
        // ---- GEMM2(c): h via cross-quad shuffle, W2 from LDS (reuse 2)
#pragma unroll
        for (int kk2 = 0; kk2 < 2; ++kk2) {
            bf16x8 hf[2];
#pragma unroll
            for (int m = 0; m < 2; ++m) {
                const int ja = kk2 * 2, jb = ja + 1;
                const unsigned va_lo = __shfl(pkl[m][ja], lA);
                const unsigned vb_lo = __shfl(pkl[m][jb], lA);
                const unsigned va_hi = __shfl(pkh[m][ja], lA);
                const unsigned vb_hi = __shfl(pkh[m][jb], lA);
                const unsigned wa_lo = __shfl(pkl[m][ja], lA + 16);
                const unsigned wb_lo = __shfl(pkl[m][jb], lA + 16);
                const unsigned wa_hi = __shfl(pkh[m][ja], lA + 16);
                const unsigned wb_hi = __shfl(pkh[m][jb], lA + 16);
                union { int4 i; bf16x8 v; } u;
                u.i.x = selhi ? (int)vb_lo : (int)va_lo;
                u.i.y = selhi ? (int)vb_hi : (int)va_hi;
                u.i.z = selhi ? (int)wb_lo : (int)wa_lo;
                u.i.w = selhi ? (int)wb_hi : (int)wa_hi;
                hf[m] = u.v;
            }
#pragma unroll
            for (int f = 0; f < 16; ++f) {
                const int nn = f * 16 + m16;
                const int off = nn * 128 + ((kk2 * 64 + quad * 16) ^ ((nn & 7) << 4));
                const bf16x8 wf = *(const bf16x8*)((const char*)W2buf + off);
                acc2[0][f] = __builtin_amdgcn_mfma_f32_16x16x32_bf16(wf, hf[0], acc2[0][f], 0, 0, 0);
                acc2[1][f] = __builtin_amdgcn_mfma_f32_16x16x32_bf16(wf, hf[1], acc2[1][f], 0, 0, 0);
            }
        }
        __syncthreads();   // all W2buf reads done (drains W1[c+1], overlapped)
        // ---- stage W2[c+1] (in flight during next GEMM1 + GELU)
        if (c < 15) {
            const __hip_bfloat16* src2 = W2 + (c + 1) * 64;
#pragma unroll
            for (int r = 0; r < 8; ++r) {
                const int s = (tid << 4) + (r << 12);
                const int row = s >> 7;
                const int g = ((s >> 4) & 7) ^ (row & 7);
                async_copy16(src2 + (long)row * 1024 + g * 8, (char*)W2buf + (r << 12) + wave * 1024);
            }
        }
    }

    // ---- epilogue: bias + residual, in-place fp32
#pragma unroll
    for (int m = 0; m < 2; ++m) {
        const long grow = bm + wave * 32 + m * 16 + m16;
#pragma unroll
        for (int f = 0; f < 16; ++f) {
            const int col = f * 16 + quad * 4;
            const float4 bb = *(const float4*)(b2 + col);
            const long a = grow * 256 + col;
            const float4 r4 = *(const float4*)(io + a);
            float4 o4 = { acc2[m][f][0] + bb.x + r4.x, acc2[m][f][1] + bb.y + r4.y,
                          acc2[m][f][2] + bb.z + r4.z, acc2[m][f][3] + bb.w + r4.w };
            *(float4*)(io + a) = o4;
        }
    }
}

// MFMA attention: one wave per (window, head); block = 4 waves.
__global__ __launch_bounds__(256) void attn_mfma_kernel(
    const __hip_bfloat16* __restrict__ qkv,
    const float* __restrict__ cbt,
    __hip_bfloat16* __restrict__ yout)
{
    __shared__ __bf16 P[4][64][PLD];
    const int tid = threadIdx.x;
    const int wave = tid >> 6, lane = tid & 63;
    const int bw = blockIdx.x >> 1;
    const int head = (blockIdx.x & 1) * 4 + wave;
    const int m16 = lane & 15, quad = lane >> 4;
    const int wi = bw & 255;
    const int hb = wi >> 3, wb = wi & 7;
    const int cls = ((hb == 31) ? 2 : 0) + ((wb == 7) ? 1 : 0);

    const __bf16* qb = (const __bf16*)qkv + (long)bw * TPW * 768 + head * 32;

    bf16x8 qf[4], kf[4];
#pragma unroll
    for (int i = 0; i < 4; ++i) {
        const int n = i * 16 + m16;
        bf16x8 q = {}, k = {};
        if (n < TPW) {
            const __bf16* p = qb + (long)n * 768 + quad * 8;
            q = *(const bf16x8*)p;
            k = *(const bf16x8*)(p + 256);
        }
        qf[i] = q; kf[i] = k;
    }

    bf16x8 vf[2][2];
#pragma unroll
    for (int jt = 0; jt < 2; ++jt)
#pragma unroll
        for (int kt = 0; kt < 2; ++kt) {
            bf16x8 v = {};
#pragma unroll
            for (int j = 0; j < 8; ++j) {
                const int tok = kt * 32 + quad * 8 + j;
                if (tok < TPW) v[j] = qb[(long)tok * 768 + 512 + jt * 16 + m16];
            }
            vf[jt][kt] = v;
        }

    // S = Q K^T (C-layout: lane holds S[n=i*16+quad*4+r][m=j*16+m16])
    f32x4 s[4][4] = {};
#pragma unroll
    for (int i = 0; i < 4; ++i)
#pragma unroll
        for (int j = 0; j < 4; ++j)
            s[i][j] = __builtin_amdgcn_mfma_f32_16x16x32_bf16(qf[i], kf[j], s[i][j], 0, 0, 0);

    const float* cb = cbt + (long)(cls * 8 + head) * 64 * 64;   // [m][n]
#pragma unroll
    for (int j = 0; j < 4; ++j) {
        const int m = j * 16 + m16;
#pragma unroll
        for (int i = 0; i < 4; ++i) {
            const float4 c = *(const float4*)(cb + m * 64 + i * 16 + quad * 4);
            s[i][j][0] = s[i][j][0] * 0.17677669529663687f + c.x;
            s[i][j][1] = s[i][j][1] * 0.17677669529663687f + c.y;
            s[i][j][2] = s[i][j][2] * 0.17677669529663687f + c.z;
            s[i][j][3] = s[i][j][3] * 0.17677669529663687f + c.w;
        }
    }

    // row softmax; normalized P -> LDS
#pragma unroll
    for (int i = 0; i < 4; ++i) {
#pragma unroll
        for (int r = 0; r < 4; ++r) {
            float mx = fmaxf(fmaxf(s[i][0][r], s[i][1][r]), fmaxf(s[i][2][r], s[i][3][r]));
            mx = fmaxf(mx, __shfl_xor(mx, 1));
            mx = fmaxf(mx, __shfl_xor(mx, 2));
            mx = fmaxf(mx, __shfl_xor(mx, 4));
            mx = fmaxf(mx, __shfl_xor(mx, 8));
            float sum = 0.0f;
#pragma unroll
            for (int j = 0; j < 4; ++j) {
                const float e = __expf(s[i][j][r] - mx);
                s[i][j][r] = e;
                sum += e;
            }
            sum += __shfl_xor(sum, 1);
            sum += __shfl_xor(sum, 2);
            sum += __shfl_xor(sum, 4);
            sum += __shfl_xor(sum, 8);
            const float inv = 1.0f / sum;
#pragma unroll
            for (int j = 0; j < 4; ++j)
                P[wave][i * 16 + quad * 4 + r][j * 16 + m16] = to_bf16(s[i][j][r] * inv);
        }
    }

    // O = P V, swapped operands: lane holds O[tok=i*16+m16][d=jt*16+quad*4+r]
    f32x4 o[4][2] = {};
#pragma unroll
    for (int kt = 0; kt < 2; ++kt)
#pragma unroll
        for (int i = 0; i < 4; ++i) {
            const bf16x8 pf = *(const bf16x8*)&P[wave][i * 16 + m16][kt * 32 + quad * 8];
#pragma unroll
            for (int jt = 0; jt < 2; ++jt)
                o[i][jt] = __builtin_amdgcn_mfma_f32_16x16x32_bf16(vf[jt][kt], pf, o[i][jt], 0, 0, 0);
        }

#pragma unroll
    for (int i = 0; i < 4; ++i) {
        const int tok = i * 16 + m16;
        if (tok < TPW) {
#pragma unroll
            for (int jt = 0; jt < 2; ++jt) {
                short4 pk;
                { __bf16 h = to_bf16(o[i][jt][0]); pk.x = *(short*)&h; }
                { __bf16 h = to_bf16(o[i][jt][1]); pk.y = *(short*)&h; }
                { __bf16 h = to_bf16(o[i][jt][2]); pk.z = *(short*)&h; }
                { __bf16 h = to_bf16(o[i][jt][3]); pk.w = *(short*)&h; }
                *(short4*)((short*)yout + ((long)bw * TPW + tok) * CDIM + head * 32 + jt * 16 + quad * 4) = pk;
            }
        }
    }
}

extern "C" void kernel_launch(void* const* d_in, const int* in_sizes, int n_in,
                              void* d_out, int out_size, void* d_ws, size_t ws_size,
                              hipStream_t stream) {
    (void)in_sizes; (void)n_in; (void)out_size; (void)ws_size;
    const float* x1     = (const float*)d_in[0];
    const float* n1g    = (const float*)d_in[2];
    const float* n1b    = (const float*)d_in[3];
    const float* qkv_w  = (const float*)d_in[4];
    const float* qkv_b  = (const float*)d_in[5];
    const float* proj_w = (const float*)d_in[6];
    const float* proj_b = (const float*)d_in[7];
    const float* rpb    = (const float*)d_in[8];
    const float* n2g    = (const float*)d_in[9];
    const float* n2b    = (const float*)d_in[10];
    const float* fc1_w  = (const float*)d_in[11];
    const float* fc1_b  = (const float*)d_in[12];
    const float* fc2_w  = (const float*)d_in[13];
    const float* fc2_b  = (const float*)d_in[14];

    float* out_x1 = (float*)d_out;
    float* out_y  = out_x1 + (long)MTOK * CDIM;

    char* ws = (char*)d_ws;
    const size_t SZ_A   = (size_t)MTOK * CDIM * sizeof(__hip_bfloat16);   // 25.7 MB
    const size_t SZ_BIG = (size_t)MTOK * 1024 * sizeof(__hip_bfloat16);   // 102.8 MB
    __hip_bfloat16* A    = (__hip_bfloat16*)ws;            // ln1 out -> yattn -> ln2 out
    char*           BIG  = ws + SZ_A;                      // qkv bf16
    __hip_bfloat16* qkvb = (__hip_bfloat16*)BIG;
    __hip_bfloat16* wB   = (__hip_bfloat16*)(ws + SZ_A + SZ_BIG);
    __hip_bfloat16* qkv_wb  = wB;               // 196608
    __hip_bfloat16* proj_wb = wB + 196608;      // 65536
    __hip_bfloat16* fc1_wb  = wB + 262144;      // 262144
    __hip_bfloat16* fc2_wb  = wB + 524288;      // 262144
    float* cbt = (float*)(wB + 786432);         // 512 KB

    // 0) weights -> bf16 (one launch); combined bias/mask table
    castall_kernel<<<3072, 256, 0, stream>>>(qkv_w, proj_w, fc1_w, fc2_w, wB);
    cb_kernel<<<32, 256, 0, stream>>>(rpb, cbt);
    // 1) LN1 + roll + window partition (bf16); one wave per token
    ln1_window_kernel<<<MTOK / 4, 256, 0, stream>>>(x1, n1g, n1b, A);
    // 2) QKV gemm -> bf16
    gemm_mfma<0, __hip_bfloat16><<<dim3(768 / 128, MTOK / 128), 256, 0, stream>>>(
        A, qkv_wb, qkv_b, qkvb, MTOK, CDIM, 768, nullptr, nullptr);
    // 3) windowed attention (MFMA) -> bf16 (into A)
    attn_mfma_kernel<<<NWIN * 2, 256, 0, stream>>>(qkvb, cbt, A);
    // 4) proj + fused scatter: writes out_y and x1b (into out_x1)
    gemm_mfma<3, float><<<dim3(256 / 128, MTOK / 128), 256, 0, stream>>>(
        A, proj_wb, proj_b, out_x1, MTOK, CDIM, CDIM, x1, out_y);
    // 5) LN2 -> bf16 (into A); one wave per token
    ln_kernel<<<MTOK / 4, 256, 0, stream>>>(out_x1, n2g, n2b, A);
    // 6+7) fused MLP v2: out_x1 += GELU(A @ fc1^T + b1) @ fc2^T + b2
    fused_mlp_kernel<<<MTOK / 128, 256, 0, stream>>>(
        A, fc1_wb, fc1_b, fc2_wb, fc2_b, out_x1);
}

// Round 5
// 462.969 us; speedup vs baseline: 1.4337x; 1.4337x over previous
//
#include <hip/hip_runtime.h>
#include <hip/hip_bf16.h>
#include <cmath>

#define CDIM 256
#define TPW 49
#define NWIN 1024
#define MTOK (NWIN * TPW)   // 50176 tokens (windowed order)
#define NHEAD 8
#define GH 224
#define GW 56
#define PLD 72              // padded LDS row (bf16 elems)

typedef __attribute__((ext_vector_type(8))) __bf16 bf16x8;
typedef __attribute__((ext_vector_type(4))) float f32x4;

__device__ __forceinline__ __bf16 to_bf16(float f) {
    __hip_bfloat16 h = __float2bfloat16(f);
    return *(__bf16*)&h;
}

__device__ __forceinline__ void async_copy16(const void* g, void* l) {
    __builtin_amdgcn_global_load_lds(
        (const __attribute__((address_space(1))) void*)g,
        (__attribute__((address_space(3))) void*)l, 16, 0, 0);
}

__device__ __forceinline__ float wave_sum(float v) {
    v += __shfl_down(v, 32);
    v += __shfl_down(v, 16);
    v += __shfl_down(v, 8);
    v += __shfl_down(v, 4);
    v += __shfl_down(v, 2);
    v += __shfl_down(v, 1);
    return v;
}

// all four weight tensors -> bf16, one launch
__global__ __launch_bounds__(256) void castall_kernel(
    const float* __restrict__ qw, const float* __restrict__ pw,
    const float* __restrict__ f1, const float* __restrict__ f2,
    __hip_bfloat16* __restrict__ dst)
{
    const int i = blockIdx.x * 256 + threadIdx.x;
    float v;
    if (i < 196608) v = qw[i];
    else if (i < 262144) v = pw[i - 196608];
    else if (i < 524288) v = f1[i - 262144];
    else v = f2[i - 524288];
    dst[i] = __float2bfloat16(v);
}

// Combined rel-pos bias + shift mask, transposed: cbt[cls*8+head][m][n] (64x64).
__global__ __launch_bounds__(256) void cb_kernel(
    const float* __restrict__ rpb, float* __restrict__ cbt)
{
    const int cls = blockIdx.x >> 3, head = blockIdx.x & 7;
    for (int e = threadIdx.x; e < 64 * 64; e += 256) {
        const int m = e >> 6, n = e & 63;
        float v;
        if (m >= 49 || n >= 49) v = -30000.0f;
        else {
            const int in_ = n / 7, jn = n - in_ * 7;
            const int im = m / 7, jm = m - im * 7;
            v = rpb[((in_ - im + 6) * 13 + (jn - jm + 6)) * 8 + head];
            const int hn = (cls & 2) ? 217 + in_ : in_;
            const int wn = (cls & 1) ? 49 + jn : jn;
            const int hm = (cls & 2) ? 217 + im : im;
            const int wm = (cls & 1) ? 49 + jm : jm;
            const int rn = (hn < 217 ? 0 : (hn < 221 ? 3 : 6)) + (wn < 49 ? 0 : (wn < 53 ? 1 : 2));
            const int rm = (hm < 217 ? 0 : (hm < 221 ? 3 : 6)) + (wm < 49 ? 0 : (wm < 53 ? 1 : 2));
            if (rn != rm) v -= 100.0f;
        }
        cbt[((long)blockIdx.x * 64 + m) * 64 + n] = v;
    }
}

// LN over C=256 fused with roll(-3,-3) + 7x7 window partition gather -> bf16.
// One WAVE per token (4 tokens/block).
__global__ __launch_bounds__(256) void ln1_window_kernel(
    const float* __restrict__ x1, const float* __restrict__ g,
    const float* __restrict__ b, __hip_bfloat16* __restrict__ out)
{
    const int wave = threadIdx.x >> 6, lane = threadIdx.x & 63;
    const int t = blockIdx.x * 4 + wave;
    const int bw = t / TPW, n = t - bw * TPW;
    const int bb = bw >> 8, wi = bw & 255;
    const int hb = wi >> 3, wb = wi & 7;
    const int i = n / 7, j = n - i * 7;
    int h0 = hb * 7 + i + 3; if (h0 >= GH) h0 -= GH;
    int w0 = wb * 7 + j + 3; if (w0 >= GW) w0 -= GW;
    const long src = ((long)(bb * GH + h0) * GW + w0) * CDIM + lane * 4;
    const float4 v = *(const float4*)(x1 + src);
    float s = v.x + v.y + v.z + v.w;
    s = wave_sum(s);
    const float mean = __shfl(s, 0) * (1.0f / 256.0f);
    const float4 d = { v.x - mean, v.y - mean, v.z - mean, v.w - mean };
    float s2 = d.x * d.x + d.y * d.y + d.z * d.z + d.w * d.w;
    s2 = wave_sum(s2);
    const float rstd = rsqrtf(__shfl(s2, 0) * (1.0f / 256.0f) + 1e-5f);
    const float4 g4 = *(const float4*)(g + lane * 4);
    const float4 b4 = *(const float4*)(b + lane * 4);
    short4 pk;
    { __bf16 h = to_bf16(d.x * rstd * g4.x + b4.x); pk.x = *(short*)&h; }
    { __bf16 h = to_bf16(d.y * rstd * g4.y + b4.y); pk.y = *(short*)&h; }
    { __bf16 h = to_bf16(d.z * rstd * g4.z + b4.z); pk.z = *(short*)&h; }
    { __bf16 h = to_bf16(d.w * rstd * g4.w + b4.w); pk.w = *(short*)&h; }
    *(short4*)((short*)out + (long)t * CDIM + lane * 4) = pk;
}

// Plain LN over C=256 -> bf16. One WAVE per token (4 tokens/block).
__global__ __launch_bounds__(256) void ln_kernel(
    const float* __restrict__ x, const float* __restrict__ g,
    const float* __restrict__ b, __hip_bfloat16* __restrict__ out)
{
    const int wave = threadIdx.x >> 6, lane = threadIdx.x & 63;
    const long t = (long)blockIdx.x * 4 + wave;
    const float4 v = *(const float4*)(x + t * CDIM + lane * 4);
    float s = v.x + v.y + v.z + v.w;
    s = wave_sum(s);
    const float mean = __shfl(s, 0) * (1.0f / 256.0f);
    const float4 d = { v.x - mean, v.y - mean, v.z - mean, v.w - mean };
    float s2 = d.x * d.x + d.y * d.y + d.z * d.z + d.w * d.w;
    s2 = wave_sum(s2);
    const float rstd = rsqrtf(__shfl(s2, 0) * (1.0f / 256.0f) + 1e-5f);
    const float4 g4 = *(const float4*)(g + lane * 4);
    const float4 b4 = *(const float4*)(b + lane * 4);
    short4 pk;
    { __bf16 h = to_bf16(d.x * rstd * g4.x + b4.x); pk.x = *(short*)&h; }
    { __bf16 h = to_bf16(d.y * rstd * g4.y + b4.y); pk.y = *(short*)&h; }
    { __bf16 h = to_bf16(d.z * rstd * g4.z + b4.z); pk.z = *(short*)&h; }
    { __bf16 h = to_bf16(d.w * rstd * g4.w + b4.w); pk.w = *(short*)&h; }
    *(short4*)((short*)out + t * CDIM + lane * 4) = pk;
}

// MFMA GEMM: Y[m,n] = sum_k X[m,k]*W[n,k] + bias[n]. X:(M,K) bf16, W:(N,K) bf16.
// 128x128 tile, BK=32, 256 threads = 4 waves, XCD-swizzled grid.
// v4: DOUBLE-BUFFERED LDS with issue-early prefetch — next K-tile's
// global_load_lds issued BEFORE current tile's ds_read+MFMA, ONE barrier
// per K-step. The barrier's implicit vmcnt(0) drain lands on loads that
// had the whole MFMA phase to complete (T3-minimum 2-phase).
// EPI: 0 = bias (bf16 out), 1 = bias+GELU (bf16 out), 2 = bias + fp32
// residual (fp32 out, in-place safe), 3 = proj+scatter.
template <int EPI, typename OutT>
__global__ __launch_bounds__(256) void gemm_mfma(
    const __hip_bfloat16* __restrict__ X, const __hip_bfloat16* __restrict__ W,
    const float* __restrict__ bias, OutT* __restrict__ Y,
    int M, int K, int N, const float* __restrict__ res, float* __restrict__ Y2)
{
    __shared__ __hip_bfloat16 As[2][128 * 32];
    __shared__ __hip_bfloat16 Bs[2][128 * 32];
    const int tid = threadIdx.x;
    const int wave = tid >> 6, lane = tid & 63;
    const int nwg = gridDim.x * gridDim.y;
    const int L = blockIdx.y * gridDim.x + blockIdx.x;
    const int cpx = nwg >> 3;
    const int orig = (L & 7) * cpx + (L >> 3);
    const int bxx = orig % gridDim.x;
    const int byy = orig / gridDim.x;
    const int bm = byy * 128, bn = bxx * 128;
    const int wm = (wave & 1) * 64, wn = (wave >> 1) * 64;
    const int m16 = lane & 15, quad = lane >> 4;
    const int srow = lane >> 2;
    const int scol = (lane & 3) * 8;

    const __hip_bfloat16* xb = X + (long)bm * K + scol;
    const __hip_bfloat16* wb = W + (long)bn * K + scol;
    const int rg0 = wave * 2, rg1 = wave * 2 + 1;
    const long xr0 = (long)(rg0 * 16 + srow) * K, xr1 = (long)(rg1 * 16 + srow) * K;

    f32x4 acc[4][4] = {};

    // prologue: stage tile 0 into buffer 0
    async_copy16(xb + xr0, (char*)As[0] + rg0 * 1024);
    async_copy16(wb + xr0, (char*)Bs[0] + rg0 * 1024);
    async_copy16(xb + xr1, (char*)As[0] + rg1 * 1024);
    async_copy16(wb + xr1, (char*)Bs[0] + rg1 * 1024);
    __syncthreads();

    int cur = 0;
    for (int k0 = 0; k0 < K; k0 += 32) {
        // issue next tile's loads into the other buffer (overlaps MFMA below)
        if (k0 + 32 < K) {
            const int nxt = cur ^ 1;
            async_copy16(xb + xr0 + k0 + 32, (char*)As[nxt] + rg0 * 1024);
            async_copy16(wb + xr0 + k0 + 32, (char*)Bs[nxt] + rg0 * 1024);
            async_copy16(xb + xr1 + k0 + 32, (char*)As[nxt] + rg1 * 1024);
            async_copy16(wb + xr1 + k0 + 32, (char*)Bs[nxt] + rg1 * 1024);
        }
        bf16x8 af[4], bf[4];
#pragma unroll
        for (int i = 0; i < 4; ++i)
            af[i] = *(const bf16x8*)&As[cur][(wm + i * 16 + m16) * 32 + quad * 8];
#pragma unroll
        for (int j = 0; j < 4; ++j)
            bf[j] = *(const bf16x8*)&Bs[cur][(wn + j * 16 + m16) * 32 + quad * 8];
        // swapped operands: D = C^T layout -> lane owns 4 consecutive cols
#pragma unroll
        for (int i = 0; i < 4; ++i)
#pragma unroll
            for (int j = 0; j < 4; ++j)
                acc[i][j] = __builtin_amdgcn_mfma_f32_16x16x32_bf16(bf[j], af[i], acc[i][j], 0, 0, 0);
        __syncthreads();   // lgkm: our reads done; vmcnt: prefetch landed
        cur ^= 1;
    }

#pragma unroll
    for (int i = 0; i < 4; ++i) {
        const long row = bm + wm + i * 16 + m16;
        long drow = row;
        if (EPI == 3) {
            const unsigned t = (unsigned)row;
            const unsigned bw_ = t / 49u;
            const unsigned n_ = t - bw_ * 49u;
            const unsigned bb = bw_ >> 8, wi = bw_ & 255u;
            const unsigned hb = wi >> 3, wbl = wi & 7u;
            const unsigned ii = n_ / 7u, jj = n_ - ii * 7u;
            int h0 = hb * 7 + ii + 3; if (h0 >= GH) h0 -= GH;
            int w0 = wbl * 7 + jj + 3; if (w0 >= GW) w0 -= GW;
            drow = (long)bb * (GH * GW) + h0 * GW + w0;
        }
#pragma unroll
        for (int j = 0; j < 4; ++j) {
            const int col = bn + wn + j * 16 + quad * 4;
            const float4 b4 = *(const float4*)&bias[col];
            float v[4];
            v[0] = acc[i][j][0] + b4.x;
            v[1] = acc[i][j][1] + b4.y;
            v[2] = acc[i][j][2] + b4.z;
            v[3] = acc[i][j][3] + b4.w;
            if (EPI == 1) {
#pragma unroll
                for (int r = 0; r < 4; ++r)
                    v[r] = 0.5f * v[r] * (1.0f + erff(v[r] * 0.70710678118654752f));
            }
            if (EPI == 0 || EPI == 1) {
                short4 pk;
                { __bf16 h = to_bf16(v[0]); pk.x = *(short*)&h; }
                { __bf16 h = to_bf16(v[1]); pk.y = *(short*)&h; }
                { __bf16 h = to_bf16(v[2]); pk.z = *(short*)&h; }
                { __bf16 h = to_bf16(v[3]); pk.w = *(short*)&h; }
                *(short4*)((short*)Y + row * N + col) = pk;
            } else if (EPI == 2) {
                const float4 r4 = *(const float4*)(res + row * N + col);
                float4 o4 = { v[0] + r4.x, v[1] + r4.y, v[2] + r4.z, v[3] + r4.w };
                *(float4*)((float*)Y + row * N + col) = o4;
            } else if (EPI == 3) {
                const long a = drow * 256 + col;
                const float4 x4 = *(const float4*)(res + a);
                float4 y4 = { v[0], v[1], v[2], v[3] };
                *(float4*)(Y2 + a) = y4;
                float4 s4 = { v[0] + x4.x, v[1] + x4.y, v[2] + x4.z, v[3] + x4.w };
                *(float4*)((float*)Y + a) = s4;
            }
        }
    }
}

// MFMA attention: one wave per (window, head); block = 4 waves.
__global__ __launch_bounds__(256) void attn_mfma_kernel(
    const __hip_bfloat16* __restrict__ qkv,
    const float* __restrict__ cbt,
    __hip_bfloat16* __restrict__ yout)
{
    __shared__ __bf16 P[4][64][PLD];
    const int tid = threadIdx.x;
    const int wave = tid >> 6, lane = tid & 63;
    const int bw = blockIdx.x >> 1;
    const int head = (blockIdx.x & 1) * 4 + wave;
    const int m16 = lane & 15, quad = lane >> 4;
    const int wi = bw & 255;
    const int hb = wi >> 3, wb = wi & 7;
    const int cls = ((hb == 31) ? 2 : 0) + ((wb == 7) ? 1 : 0);

    const __bf16* qb = (const __bf16*)qkv + (long)bw * TPW * 768 + head * 32;

    bf16x8 qf[4], kf[4];
#pragma unroll
    for (int i = 0; i < 4; ++i) {
        const int n = i * 16 + m16;
        bf16x8 q = {}, k = {};
        if (n < TPW) {
            const __bf16* p = qb + (long)n * 768 + quad * 8;
            q = *(const bf16x8*)p;
            k = *(const bf16x8*)(p + 256);
        }
        qf[i] = q; kf[i] = k;
    }

    bf16x8 vf[2][2];
#pragma unroll
    for (int jt = 0; jt < 2; ++jt)
#pragma unroll
        for (int kt = 0; kt < 2; ++kt) {
            bf16x8 v = {};
#pragma unroll
            for (int j = 0; j < 8; ++j) {
                const int tok = kt * 32 + quad * 8 + j;
                if (tok < TPW) v[j] = qb[(long)tok * 768 + 512 + jt * 16 + m16];
            }
            vf[jt][kt] = v;
        }

    // S = Q K^T (C-layout: lane holds S[n=i*16+quad*4+r][m=j*16+m16])
    f32x4 s[4][4] = {};
#pragma unroll
    for (int i = 0; i < 4; ++i)
#pragma unroll
        for (int j = 0; j < 4; ++j)
            s[i][j] = __builtin_amdgcn_mfma_f32_16x16x32_bf16(qf[i], kf[j], s[i][j], 0, 0, 0);

    const float* cb = cbt + (long)(cls * 8 + head) * 64 * 64;   // [m][n]
#pragma unroll
    for (int j = 0; j < 4; ++j) {
        const int m = j * 16 + m16;
#pragma unroll
        for (int i = 0; i < 4; ++i) {
            const float4 c = *(const float4*)(cb + m * 64 + i * 16 + quad * 4);
            s[i][j][0] = s[i][j][0] * 0.17677669529663687f + c.x;
            s[i][j][1] = s[i][j][1] * 0.17677669529663687f + c.y;
            s[i][j][2] = s[i][j][2] * 0.17677669529663687f + c.z;
            s[i][j][3] = s[i][j][3] * 0.17677669529663687f + c.w;
        }
    }

    // row softmax; normalized P -> LDS
#pragma unroll
    for (int i = 0; i < 4; ++i) {
#pragma unroll
        for (int r = 0; r < 4; ++r) {
            float mx = fmaxf(fmaxf(s[i][0][r], s[i][1][r]), fmaxf(s[i][2][r], s[i][3][r]));
            mx = fmaxf(mx, __shfl_xor(mx, 1));
            mx = fmaxf(mx, __shfl_xor(mx, 2));
            mx = fmaxf(mx, __shfl_xor(mx, 4));
            mx = fmaxf(mx, __shfl_xor(mx, 8));
            float sum = 0.0f;
#pragma unroll
            for (int j = 0; j < 4; ++j) {
                const float e = __expf(s[i][j][r] - mx);
                s[i][j][r] = e;
                sum += e;
            }
            sum += __shfl_xor(sum, 1);
            sum += __shfl_xor(sum, 2);
            sum += __shfl_xor(sum, 4);
            sum += __shfl_xor(sum, 8);
            const float inv = 1.0f / sum;
#pragma unroll
            for (int j = 0; j < 4; ++j)
                P[wave][i * 16 + quad * 4 + r][j * 16 + m16] = to_bf16(s[i][j][r] * inv);
        }
    }

    // O = P V, swapped operands: lane holds O[tok=i*16+m16][d=jt*16+quad*4+r]
    f32x4 o[4][2] = {};
#pragma unroll
    for (int kt = 0; kt < 2; ++kt)
#pragma unroll
        for (int i = 0; i < 4; ++i) {
            const bf16x8 pf = *(const bf16x8*)&P[wave][i * 16 + m16][kt * 32 + quad * 8];
#pragma unroll
            for (int jt = 0; jt < 2; ++jt)
                o[i][jt] = __builtin_amdgcn_mfma_f32_16x16x32_bf16(vf[jt][kt], pf, o[i][jt], 0, 0, 0);
        }

#pragma unroll
    for (int i = 0; i < 4; ++i) {
        const int tok = i * 16 + m16;
        if (tok < TPW) {
#pragma unroll
            for (int jt = 0; jt < 2; ++jt) {
                short4 pk;
                { __bf16 h = to_bf16(o[i][jt][0]); pk.x = *(short*)&h; }
                { __bf16 h = to_bf16(o[i][jt][1]); pk.y = *(short*)&h; }
                { __bf16 h = to_bf16(o[i][jt][2]); pk.z = *(short*)&h; }
                { __bf16 h = to_bf16(o[i][jt][3]); pk.w = *(short*)&h; }
                *(short4*)((short*)yout + ((long)bw * TPW + tok) * CDIM + head * 32 + jt * 16 + quad * 4) = pk;
            }
        }
    }
}

extern "C" void kernel_launch(void* const* d_in, const int* in_sizes, int n_in,
                              void* d_out, int out_size, void* d_ws, size_t ws_size,
                              hipStream_t stream) {
    (void)in_sizes; (void)n_in; (void)out_size; (void)ws_size;
    const float* x1     = (const float*)d_in[0];
    const float* n1g    = (const float*)d_in[2];
    const float* n1b    = (const float*)d_in[3];
    const float* qkv_w  = (const float*)d_in[4];
    const float* qkv_b  = (const float*)d_in[5];
    const float* proj_w = (const float*)d_in[6];
    const float* proj_b = (const float*)d_in[7];
    const float* rpb    = (const float*)d_in[8];
    const float* n2g    = (const float*)d_in[9];
    const float* n2b    = (const float*)d_in[10];
    const float* fc1_w  = (const float*)d_in[11];
    const float* fc1_b  = (const float*)d_in[12];
    const float* fc2_w  = (const float*)d_in[13];
    const float* fc2_b  = (const float*)d_in[14];

    float* out_x1 = (float*)d_out;
    float* out_y  = out_x1 + (long)MTOK * CDIM;

    char* ws = (char*)d_ws;
    const size_t SZ_A   = (size_t)MTOK * CDIM * sizeof(__hip_bfloat16);   // 25.7 MB
    const size_t SZ_BIG = (size_t)MTOK * 1024 * sizeof(__hip_bfloat16);   // 102.8 MB
    __hip_bfloat16* A    = (__hip_bfloat16*)ws;            // ln1 out -> yattn -> ln2 out
    char*           BIG  = ws + SZ_A;                      // qkv bf16 -> h1 bf16
    __hip_bfloat16* qkvb = (__hip_bfloat16*)BIG;
    __hip_bfloat16* H1   = (__hip_bfloat16*)BIG;
    __hip_bfloat16* wB   = (__hip_bfloat16*)(ws + SZ_A + SZ_BIG);
    __hip_bfloat16* qkv_wb  = wB;               // 196608
    __hip_bfloat16* proj_wb = wB + 196608;      // 65536
    __hip_bfloat16* fc1_wb  = wB + 262144;      // 262144
    __hip_bfloat16* fc2_wb  = wB + 524288;      // 262144
    float* cbt = (float*)(wB + 786432);         // 512 KB

    // 0) weights -> bf16 (one launch); combined bias/mask table
    castall_kernel<<<3072, 256, 0, stream>>>(qkv_w, proj_w, fc1_w, fc2_w, wB);
    cb_kernel<<<32, 256, 0, stream>>>(rpb, cbt);
    // 1) LN1 + roll + window partition (bf16); one wave per token
    ln1_window_kernel<<<MTOK / 4, 256, 0, stream>>>(x1, n1g, n1b, A);
    // 2) QKV gemm -> bf16
    gemm_mfma<0, __hip_bfloat16><<<dim3(768 / 128, MTOK / 128), 256, 0, stream>>>(
        A, qkv_wb, qkv_b, qkvb, MTOK, CDIM, 768, nullptr, nullptr);
    // 3) windowed attention (MFMA) -> bf16 (into A)
    attn_mfma_kernel<<<NWIN * 2, 256, 0, stream>>>(qkvb, cbt, A);
    // 4) proj + fused scatter: writes out_y and x1b (into out_x1)
    gemm_mfma<3, float><<<dim3(256 / 128, MTOK / 128), 256, 0, stream>>>(
        A, proj_wb, proj_b, out_x1, MTOK, CDIM, CDIM, x1, out_y);
    // 5) LN2 -> bf16 (into A); one wave per token
    ln_kernel<<<MTOK / 4, 256, 0, stream>>>(out_x1, n2g, n2b, A);
    // 6) fc1 + GELU -> bf16
    gemm_mfma<1, __hip_bfloat16><<<dim3(1024 / 128, MTOK / 128), 256, 0, stream>>>(
        A, fc1_wb, fc1_b, H1, MTOK, CDIM, 1024, nullptr, nullptr);
    // 7) fc2 + residual (in-place on out_x1)
    gemm_mfma<2, float><<<dim3(256 / 128, MTOK / 128), 256, 0, stream>>>(
        H1, fc2_wb, fc2_b, out_x1, MTOK, 1024, CDIM, out_x1, nullptr);
}

// Round 7
// 459.570 us; speedup vs baseline: 1.4443x; 1.0074x over previous
//
#include <hip/hip_runtime.h>
#include <hip/hip_bf16.h>
#include <cmath>

#define CDIM 256
#define TPW 49
#define NWIN 1024
#define MTOK (NWIN * TPW)   // 50176 tokens (windowed order)
#define NHEAD 8
#define GH 224
#define GW 56
#define PLD 72              // padded LDS row (bf16 elems)

typedef __attribute__((ext_vector_type(8))) __bf16 bf16x8;
typedef __attribute__((ext_vector_type(4))) float f32x4;

__device__ __forceinline__ __bf16 to_bf16(float f) {
    __hip_bfloat16 h = __float2bfloat16(f);
    return *(__bf16*)&h;
}

__device__ __forceinline__ void async_copy16(const void* g, void* l) {
    __builtin_amdgcn_global_load_lds(
        (const __attribute__((address_space(1))) void*)g,
        (__attribute__((address_space(3))) void*)l, 16, 0, 0);
}

__device__ __forceinline__ float wave_sum(float v) {
    v += __shfl_down(v, 32);
    v += __shfl_down(v, 16);
    v += __shfl_down(v, 8);
    v += __shfl_down(v, 4);
    v += __shfl_down(v, 2);
    v += __shfl_down(v, 1);
    return v;
}

// all four weight tensors -> bf16, one launch
__global__ __launch_bounds__(256) void castall_kernel(
    const float* __restrict__ qw, const float* __restrict__ pw,
    const float* __restrict__ f1, const float* __restrict__ f2,
    __hip_bfloat16* __restrict__ dst)
{
    const int i = blockIdx.x * 256 + threadIdx.x;
    float v;
    if (i < 196608) v = qw[i];
    else if (i < 262144) v = pw[i - 196608];
    else if (i < 524288) v = f1[i - 262144];
    else v = f2[i - 524288];
    dst[i] = __float2bfloat16(v);
}

// Combined rel-pos bias + shift mask, transposed: cbt[cls*8+head][m][n] (64x64).
__global__ __launch_bounds__(256) void cb_kernel(
    const float* __restrict__ rpb, float* __restrict__ cbt)
{
    const int cls = blockIdx.x >> 3, head = blockIdx.x & 7;
    for (int e = threadIdx.x; e < 64 * 64; e += 256) {
        const int m = e >> 6, n = e & 63;
        float v;
        if (m >= 49 || n >= 49) v = -30000.0f;
        else {
            const int in_ = n / 7, jn = n - in_ * 7;
            const int im = m / 7, jm = m - im * 7;
            v = rpb[((in_ - im + 6) * 13 + (jn - jm + 6)) * 8 + head];
            const int hn = (cls & 2) ? 217 + in_ : in_;
            const int wn = (cls & 1) ? 49 + jn : jn;
            const int hm = (cls & 2) ? 217 + im : im;
            const int wm = (cls & 1) ? 49 + jm : jm;
            const int rn = (hn < 217 ? 0 : (hn < 221 ? 3 : 6)) + (wn < 49 ? 0 : (wn < 53 ? 1 : 2));
            const int rm = (hm < 217 ? 0 : (hm < 221 ? 3 : 6)) + (wm < 49 ? 0 : (wm < 53 ? 1 : 2));
            if (rn != rm) v -= 100.0f;
        }
        cbt[((long)blockIdx.x * 64 + m) * 64 + n] = v;
    }
}

// LN over C=256 fused with roll(-3,-3) + 7x7 window partition gather -> bf16.
// One WAVE per token (4 tokens/block).
__global__ __launch_bounds__(256) void ln1_window_kernel(
    const float* __restrict__ x1, const float* __restrict__ g,
    const float* __restrict__ b, __hip_bfloat16* __restrict__ out)
{
    const int wave = threadIdx.x >> 6, lane = threadIdx.x & 63;
    const int t = blockIdx.x * 4 + wave;
    const int bw = t / TPW, n = t - bw * TPW;
    const int bb = bw >> 8, wi = bw & 255;
    const int hb = wi >> 3, wb = wi & 7;
    const int i = n / 7, j = n - i * 7;
    int h0 = hb * 7 + i + 3; if (h0 >= GH) h0 -= GH;
    int w0 = wb * 7 + j + 3; if (w0 >= GW) w0 -= GW;
    const long src = ((long)(bb * GH + h0) * GW + w0) * CDIM + lane * 4;
    const float4 v = *(const float4*)(x1 + src);
    float s = v.x + v.y + v.z + v.w;
    s = wave_sum(s);
    const float mean = __shfl(s, 0) * (1.0f / 256.0f);
    const float4 d = { v.x - mean, v.y - mean, v.z - mean, v.w - mean };
    float s2 = d.x * d.x + d.y * d.y + d.z * d.z + d.w * d.w;
    s2 = wave_sum(s2);
    const float rstd = rsqrtf(__shfl(s2, 0) * (1.0f / 256.0f) + 1e-5f);
    const float4 g4 = *(const float4*)(g + lane * 4);
    const float4 b4 = *(const float4*)(b + lane * 4);
    short4 pk;
    { __bf16 h = to_bf16(d.x * rstd * g4.x + b4.x); pk.x = *(short*)&h; }
    { __bf16 h = to_bf16(d.y * rstd * g4.y + b4.y); pk.y = *(short*)&h; }
    { __bf16 h = to_bf16(d.z * rstd * g4.z + b4.z); pk.z = *(short*)&h; }
    { __bf16 h = to_bf16(d.w * rstd * g4.w + b4.w); pk.w = *(short*)&h; }
    *(short4*)((short*)out + (long)t * CDIM + lane * 4) = pk;
}

// Plain LN over C=256 -> bf16. One WAVE per token (4 tokens/block).
__global__ __launch_bounds__(256) void ln_kernel(
    const float* __restrict__ x, const float* __restrict__ g,
    const float* __restrict__ b, __hip_bfloat16* __restrict__ out)
{
    const int wave = threadIdx.x >> 6, lane = threadIdx.x & 63;
    const long t = (long)blockIdx.x * 4 + wave;
    const float4 v = *(const float4*)(x + t * CDIM + lane * 4);
    float s = v.x + v.y + v.z + v.w;
    s = wave_sum(s);
    const float mean = __shfl(s, 0) * (1.0f / 256.0f);
    const float4 d = { v.x - mean, v.y - mean, v.z - mean, v.w - mean };
    float s2 = d.x * d.x + d.y * d.y + d.z * d.z + d.w * d.w;
    s2 = wave_sum(s2);
    const float rstd = rsqrtf(__shfl(s2, 0) * (1.0f / 256.0f) + 1e-5f);
    const float4 g4 = *(const float4*)(g + lane * 4);
    const float4 b4 = *(const float4*)(b + lane * 4);
    short4 pk;
    { __bf16 h = to_bf16(d.x * rstd * g4.x + b4.x); pk.x = *(short*)&h; }
    { __bf16 h = to_bf16(d.y * rstd * g4.y + b4.y); pk.y = *(short*)&h; }
    { __bf16 h = to_bf16(d.z * rstd * g4.z + b4.z); pk.z = *(short*)&h; }
    { __bf16 h = to_bf16(d.w * rstd * g4.w + b4.w); pk.w = *(short*)&h; }
    *(short4*)((short*)out + t * CDIM + lane * 4) = pk;
}

// MFMA GEMM: Y[m,n] = sum_k X[m,k]*W[n,k] + bias[n]. X:(M,K) bf16, W:(N,K) bf16.
// 128x128 tile, BK=32, 256 threads = 4 waves, XCD-swizzled grid.
// v5b: 3-deep staged pipeline with COUNTED vmcnt (T4) — raw s_barrier +
// s_waitcnt vmcnt(8/4/0); stages k+1,k+2 stay in flight across barriers,
// so stage(k) has ~2 K-steps (>> HBM latency) to land. Never vmcnt(0)
// in steady state. End-of-step lgkmcnt(0)+barrier protects buffer reuse
// (iteration k+1 overwrites exactly buf[k%3]). sched_barrier(0) after
// each waitcnt pins hipcc from hoisting dependent ops (rule #18).
// EPI: 0 = bias (bf16 out), 1 = bias+GELU (bf16 out), 2 = bias + fp32
// residual (fp32 out, in-place safe), 3 = proj+scatter.
template <int EPI, typename OutT>
__global__ __launch_bounds__(256) void gemm_mfma(
    const __hip_bfloat16* __restrict__ X, const __hip_bfloat16* __restrict__ W,
    const float* __restrict__ bias, OutT* __restrict__ Y,
    int M, int K, int N, const float* __restrict__ res, float* __restrict__ Y2)
{
    __shared__ __hip_bfloat16 As[3][128 * 32];
    __shared__ __hip_bfloat16 Bs[3][128 * 32];
    const int tid = threadIdx.x;
    const int wave = tid >> 6, lane = tid & 63;
    const int nwg = gridDim.x * gridDim.y;
    const int L = blockIdx.y * gridDim.x + blockIdx.x;
    const int cpx = nwg >> 3;
    const int orig = (L & 7) * cpx + (L >> 3);
    const int bxx = orig % gridDim.x;
    const int byy = orig / gridDim.x;
    const int bm = byy * 128, bn = bxx * 128;
    const int wm = (wave & 1) * 64, wn = (wave >> 1) * 64;
    const int m16 = lane & 15, quad = lane >> 4;
    const int srow = lane >> 2;
    const int scol = (lane & 3) * 8;

    const __hip_bfloat16* xb = X + (long)bm * K + scol;
    const __hip_bfloat16* wb = W + (long)bn * K + scol;
    const int rg0 = wave * 2, rg1 = wave * 2 + 1;
    const long xr0 = (long)(rg0 * 16 + srow) * K, xr1 = (long)(rg1 * 16 + srow) * K;

    f32x4 acc[4][4] = {};
    const int NK = K >> 5;

    // prologue: issue stages 0 and 1 (4 loads each per wave)
    async_copy16(xb + xr0, (char*)As[0] + rg0 * 1024);
    async_copy16(wb + xr0, (char*)Bs[0] + rg0 * 1024);
    async_copy16(xb + xr1, (char*)As[0] + rg1 * 1024);
    async_copy16(wb + xr1, (char*)Bs[0] + rg1 * 1024);
    async_copy16(xb + xr0 + 32, (char*)As[1] + rg0 * 1024);
    async_copy16(wb + xr0 + 32, (char*)Bs[1] + rg0 * 1024);
    async_copy16(xb + xr1 + 32, (char*)As[1] + rg1 * 1024);
    async_copy16(wb + xr1 + 32, (char*)Bs[1] + rg1 * 1024);
    asm volatile("s_waitcnt vmcnt(4)" ::: "memory");   // stage 0 landed
    __builtin_amdgcn_sched_barrier(0);
    __builtin_amdgcn_s_barrier();

    for (int k = 0; k < NK; ++k) {
        const int kb = k % 3;
        if (k + 2 < NK) {
            // overwrite buf[(k+2)%3] == buf[(k-1)%3]: its reads retired at
            // the lgkmcnt(0)+barrier ending iteration k-1.
            const int nb = (k + 2) % 3;
            const long ko = (long)(k + 2) * 32;
            async_copy16(xb + xr0 + ko, (char*)As[nb] + rg0 * 1024);
            async_copy16(wb + xr0 + ko, (char*)Bs[nb] + rg0 * 1024);
            async_copy16(xb + xr1 + ko, (char*)As[nb] + rg1 * 1024);
            async_copy16(wb + xr1 + ko, (char*)Bs[nb] + rg1 * 1024);
            asm volatile("s_waitcnt vmcnt(8)" ::: "memory");   // stage k landed
        } else if (k + 1 < NK) {
            asm volatile("s_waitcnt vmcnt(4)" ::: "memory");
        } else {
            asm volatile("s_waitcnt vmcnt(0)" ::: "memory");
        }
        __builtin_amdgcn_sched_barrier(0);
        __builtin_amdgcn_s_barrier();   // all waves' stage(k) visible

        bf16x8 af[4], bf[4];
#pragma unroll
        for (int i = 0; i < 4; ++i)
            af[i] = *(const bf16x8*)&As[kb][(wm + i * 16 + m16) * 32 + quad * 8];
#pragma unroll
        for (int j = 0; j < 4; ++j)
            bf[j] = *(const bf16x8*)&Bs[kb][(wn + j * 16 + m16) * 32 + quad * 8];
        // swapped operands: D = C^T layout -> lane owns 4 consecutive cols
#pragma unroll
        for (int i = 0; i < 4; ++i)
#pragma unroll
            for (int j = 0; j < 4; ++j)
                acc[i][j] = __builtin_amdgcn_mfma_f32_16x16x32_bf16(bf[j], af[i], acc[i][j], 0, 0, 0);

        asm volatile("s_waitcnt lgkmcnt(0)" ::: "memory");  // our ds_reads retired
        __builtin_amdgcn_sched_barrier(0);
        __builtin_amdgcn_s_barrier();   // buf[kb] free for overwrite next iter
    }

#pragma unroll
    for (int i = 0; i < 4; ++i) {
        const long row = bm + wm + i * 16 + m16;
        long drow = row;
        if (EPI == 3) {
            const unsigned t = (unsigned)row;
            const unsigned bw_ = t / 49u;
            const unsigned n_ = t - bw_ * 49u;
            const unsigned bb = bw_ >> 8, wi = bw_ & 255u;
            const unsigned hb = wi >> 3, wbl = wi & 7u;
            const unsigned ii = n_ / 7u, jj = n_ - ii * 7u;
            int h0 = hb * 7 + ii + 3; if (h0 >= GH) h0 -= GH;
            int w0 = wbl * 7 + jj + 3; if (w0 >= GW) w0 -= GW;
            drow = (long)bb * (GH * GW) + h0 * GW + w0;
        }
#pragma unroll
        for (int j = 0; j < 4; ++j) {
            const int col = bn + wn + j * 16 + quad * 4;
            const float4 b4 = *(const float4*)&bias[col];
            float v[4];
            v[0] = acc[i][j][0] + b4.x;
            v[1] = acc[i][j][1] + b4.y;
            v[2] = acc[i][j][2] + b4.z;
            v[3] = acc[i][j][3] + b4.w;
            if (EPI == 1) {
#pragma unroll
                for (int r = 0; r < 4; ++r)
                    v[r] = 0.5f * v[r] * (1.0f + erff(v[r] * 0.70710678118654752f));
            }
            if (EPI == 0 || EPI == 1) {
                short4 pk;
                { __bf16 h = to_bf16(v[0]); pk.x = *(short*)&h; }
                { __bf16 h = to_bf16(v[1]); pk.y = *(short*)&h; }
                { __bf16 h = to_bf16(v[2]); pk.z = *(short*)&h; }
                { __bf16 h = to_bf16(v[3]); pk.w = *(short*)&h; }
                *(short4*)((short*)Y + row * N + col) = pk;
            } else if (EPI == 2) {
                const float4 r4 = *(const float4*)(res + row * N + col);
                float4 o4 = { v[0] + r4.x, v[1] + r4.y, v[2] + r4.z, v[3] + r4.w };
                *(float4*)((float*)Y + row * N + col) = o4;
            } else if (EPI == 3) {
                const long a = drow * 256 + col;
                const float4 x4 = *(const float4*)(res + a);
                float4 y4 = { v[0], v[1], v[2], v[3] };
                *(float4*)(Y2 + a) = y4;
                float4 s4 = { v[0] + x4.x, v[1] + x4.y, v[2] + x4.z, v[3] + x4.w };
                *(float4*)((float*)Y + a) = s4;
            }
        }
    }
}

// MFMA attention: one wave per (window, head); block = 4 waves.
__global__ __launch_bounds__(256) void attn_mfma_kernel(
    const __hip_bfloat16* __restrict__ qkv,
    const float* __restrict__ cbt,
    __hip_bfloat16* __restrict__ yout)
{
    __shared__ __bf16 P[4][64][PLD];
    const int tid = threadIdx.x;
    const int wave = tid >> 6, lane = tid & 63;
    const int bw = blockIdx.x >> 1;
    const int head = (blockIdx.x & 1) * 4 + wave;
    const int m16 = lane & 15, quad = lane >> 4;
    const int wi = bw & 255;
    const int hb = wi >> 3, wb = wi & 7;
    const int cls = ((hb == 31) ? 2 : 0) + ((wb == 7) ? 1 : 0);

    const __bf16* qb = (const __bf16*)qkv + (long)bw * TPW * 768 + head * 32;

    bf16x8 qf[4], kf[4];
#pragma unroll
    for (int i = 0; i < 4; ++i) {
        const int n = i * 16 + m16;
        bf16x8 q = {}, k = {};
        if (n < TPW) {
            const __bf16* p = qb + (long)n * 768 + quad * 8;
            q = *(const bf16x8*)p;
            k = *(const bf16x8*)(p + 256);
        }
        qf[i] = q; kf[i] = k;
    }

    bf16x8 vf[2][2];
#pragma unroll
    for (int jt = 0; jt < 2; ++jt)
#pragma unroll
        for (int kt = 0; kt < 2; ++kt) {
            bf16x8 v = {};
#pragma unroll
            for (int j = 0; j < 8; ++j) {
                const int tok = kt * 32 + quad * 8 + j;
                if (tok < TPW) v[j] = qb[(long)tok * 768 + 512 + jt * 16 + m16];
            }
            vf[jt][kt] = v;
        }

    // S = Q K^T (C-layout: lane holds S[n=i*16+quad*4+r][m=j*16+m16])
    f32x4 s[4][4] = {};
#pragma unroll
    for (int i = 0; i < 4; ++i)
#pragma unroll
        for (int j = 0; j < 4; ++j)
            s[i][j] = __builtin_amdgcn_mfma_f32_16x16x32_bf16(qf[i], kf[j], s[i][j], 0, 0, 0);

    const float* cb = cbt + (long)(cls * 8 + head) * 64 * 64;   // [m][n]
#pragma unroll
    for (int j = 0; j < 4; ++j) {
        const int m = j * 16 + m16;
#pragma unroll
        for (int i = 0; i < 4; ++i) {
            const float4 c = *(const float4*)(cb + m * 64 + i * 16 + quad * 4);
            s[i][j][0] = s[i][j][0] * 0.17677669529663687f + c.x;
            s[i][j][1] = s[i][j][1] * 0.17677669529663687f + c.y;
            s[i][j][2] = s[i][j][2] * 0.17677669529663687f + c.z;
            s[i][j][3] = s[i][j][3] * 0.17677669529663687f + c.w;
        }
    }

    // row softmax; normalized P -> LDS
#pragma unroll
    for (int i = 0; i < 4; ++i) {
#pragma unroll
        for (int r = 0; r < 4; ++r) {
            float mx = fmaxf(fmaxf(s[i][0][r], s[i][1][r]), fmaxf(s[i][2][r], s[i][3][r]));
            mx = fmaxf(mx, __shfl_xor(mx, 1));
            mx = fmaxf(mx, __shfl_xor(mx, 2));
            mx = fmaxf(mx, __shfl_xor(mx, 4));
            mx = fmaxf(mx, __shfl_xor(mx, 8));
            float sum = 0.0f;
#pragma unroll
            for (int j = 0; j < 4; ++j) {
                const float e = __expf(s[i][j][r] - mx);
                s[i][j][r] = e;
                sum += e;
            }
            sum += __shfl_xor(sum, 1);
            sum += __shfl_xor(sum, 2);
            sum += __shfl_xor(sum, 4);
            sum += __shfl_xor(sum, 8);
            const float inv = 1.0f / sum;
#pragma unroll
            for (int j = 0; j < 4; ++j)
                P[wave][i * 16 + quad * 4 + r][j * 16 + m16] = to_bf16(s[i][j][r] * inv);
        }
    }

    // O = P V, swapped operands: lane holds O[tok=i*16+m16][d=jt*16+quad*4+r]
    f32x4 o[4][2] = {};
#pragma unroll
    for (int kt = 0; kt < 2; ++kt)
#pragma unroll
        for (int i = 0; i < 4; ++i) {
            const bf16x8 pf = *(const bf16x8*)&P[wave][i * 16 + m16][kt * 32 + quad * 8];
#pragma unroll
            for (int jt = 0; jt < 2; ++jt)
                o[i][jt] = __builtin_amdgcn_mfma_f32_16x16x32_bf16(vf[jt][kt], pf, o[i][jt], 0, 0, 0);
        }

#pragma unroll
    for (int i = 0; i < 4; ++i) {
        const int tok = i * 16 + m16;
        if (tok < TPW) {
#pragma unroll
            for (int jt = 0; jt < 2; ++jt) {
                short4 pk;
                { __bf16 h = to_bf16(o[i][jt][0]); pk.x = *(short*)&h; }
                { __bf16 h = to_bf16(o[i][jt][1]); pk.y = *(short*)&h; }
                { __bf16 h = to_bf16(o[i][jt][2]); pk.z = *(short*)&h; }
                { __bf16 h = to_bf16(o[i][jt][3]); pk.w = *(short*)&h; }
                *(short4*)((short*)yout + ((long)bw * TPW + tok) * CDIM + head * 32 + jt * 16 + quad * 4) = pk;
            }
        }
    }
}

extern "C" void kernel_launch(void* const* d_in, const int* in_sizes, int n_in,
                              void* d_out, int out_size, void* d_ws, size_t ws_size,
                              hipStream_t stream) {
    (void)in_sizes; (void)n_in; (void)out_size; (void)ws_size;
    const float* x1     = (const float*)d_in[0];
    const float* n1g    = (const float*)d_in[2];
    const float* n1b    = (const float*)d_in[3];
    const float* qkv_w  = (const float*)d_in[4];
    const float* qkv_b  = (const float*)d_in[5];
    const float* proj_w = (const float*)d_in[6];
    const float* proj_b = (const float*)d_in[7];
    const float* rpb    = (const float*)d_in[8];
    const float* n2g    = (const float*)d_in[9];
    const float* n2b    = (const float*)d_in[10];
    const float* fc1_w  = (const float*)d_in[11];
    const float* fc1_b  = (const float*)d_in[12];
    const float* fc2_w  = (const float*)d_in[13];
    const float* fc2_b  = (const float*)d_in[14];

    float* out_x1 = (float*)d_out;
    float* out_y  = out_x1 + (long)MTOK * CDIM;

    char* ws = (char*)d_ws;
    const size_t SZ_A   = (size_t)MTOK * CDIM * sizeof(__hip_bfloat16);   // 25.7 MB
    const size_t SZ_BIG = (size_t)MTOK * 1024 * sizeof(__hip_bfloat16);   // 102.8 MB
    __hip_bfloat16* A    = (__hip_bfloat16*)ws;            // ln1 out -> yattn -> ln2 out
    char*           BIG  = ws + SZ_A;                      // qkv bf16 -> h1 bf16
    __hip_bfloat16* qkvb = (__hip_bfloat16*)BIG;
    __hip_bfloat16* H1   = (__hip_bfloat16*)BIG;
    __hip_bfloat16* wB   = (__hip_bfloat16*)(ws + SZ_A + SZ_BIG);
    __hip_bfloat16* qkv_wb  = wB;               // 196608
    __hip_bfloat16* proj_wb = wB + 196608;      // 65536
    __hip_bfloat16* fc1_wb  = wB + 262144;      // 262144
    __hip_bfloat16* fc2_wb  = wB + 524288;      // 262144
    float* cbt = (float*)(wB + 786432);         // 512 KB

    // 0) weights -> bf16 (one launch); combined bias/mask table
    castall_kernel<<<3072, 256, 0, stream>>>(qkv_w, proj_w, fc1_w, fc2_w, wB);
    cb_kernel<<<32, 256, 0, stream>>>(rpb, cbt);
    // 1) LN1 + roll + window partition (bf16); one wave per token
    ln1_window_kernel<<<MTOK / 4, 256, 0, stream>>>(x1, n1g, n1b, A);
    // 2) QKV gemm -> bf16
    gemm_mfma<0, __hip_bfloat16><<<dim3(768 / 128, MTOK / 128), 256, 0, stream>>>(
        A, qkv_wb, qkv_b, qkvb, MTOK, CDIM, 768, nullptr, nullptr);
    // 3) windowed attention (MFMA) -> bf16 (into A)
    attn_mfma_kernel<<<NWIN * 2, 256, 0, stream>>>(qkvb, cbt, A);
    // 4) proj + fused scatter: writes out_y and x1b (into out_x1)
    gemm_mfma<3, float><<<dim3(256 / 128, MTOK / 128), 256, 0, stream>>>(
        A, proj_wb, proj_b, out_x1, MTOK, CDIM, CDIM, x1, out_y);
    // 5) LN2 -> bf16 (into A); one wave per token
    ln_kernel<<<MTOK / 4, 256, 0, stream>>>(out_x1, n2g, n2b, A);
    // 6) fc1 + GELU -> bf16
    gemm_mfma<1, __hip_bfloat16><<<dim3(1024 / 128, MTOK / 128), 256, 0, stream>>>(
        A, fc1_wb, fc1_b, H1, MTOK, CDIM, 1024, nullptr, nullptr);
    // 7) fc2 + residual (in-place on out_x1)
    gemm_mfma<2, float><<<dim3(256 / 128, MTOK / 128), 256, 0, stream>>>(
        H1, fc2_wb, fc2_b, out_x1, MTOK, 1024, CDIM, out_x1, nullptr);
}

// Round 8
// 438.110 us; speedup vs baseline: 1.5151x; 1.0490x over previous
//
#include <hip/hip_runtime.h>
#include <hip/hip_bf16.h>
#include <cmath>

#define CDIM 256
#define TPW 49
#define NWIN 1024
#define MTOK (NWIN * TPW)   // 50176 tokens (windowed order)
#define NHEAD 8
#define GH 224
#define GW 56
#define PLD 72              // padded LDS row (bf16 elems)

typedef __attribute__((ext_vector_type(8))) __bf16 bf16x8;
typedef __attribute__((ext_vector_type(4))) float f32x4;

__device__ __forceinline__ __bf16 to_bf16(float f) {
    __hip_bfloat16 h = __float2bfloat16(f);
    return *(__bf16*)&h;
}

__device__ __forceinline__ void async_copy16(const void* g, void* l) {
    __builtin_amdgcn_global_load_lds(
        (const __attribute__((address_space(1))) void*)g,
        (__attribute__((address_space(3))) void*)l, 16, 0, 0);
}

__device__ __forceinline__ float wave_sum(float v) {
    v += __shfl_down(v, 32);
    v += __shfl_down(v, 16);
    v += __shfl_down(v, 8);
    v += __shfl_down(v, 4);
    v += __shfl_down(v, 2);
    v += __shfl_down(v, 1);
    return v;
}

// all four weight tensors -> bf16, one launch
__global__ __launch_bounds__(256) void castall_kernel(
    const float* __restrict__ qw, const float* __restrict__ pw,
    const float* __restrict__ f1, const float* __restrict__ f2,
    __hip_bfloat16* __restrict__ dst)
{
    const int i = blockIdx.x * 256 + threadIdx.x;
    float v;
    if (i < 196608) v = qw[i];
    else if (i < 262144) v = pw[i - 196608];
    else if (i < 524288) v = f1[i - 262144];
    else v = f2[i - 524288];
    dst[i] = __float2bfloat16(v);
}

// Combined rel-pos bias + shift mask, transposed: cbt[cls*8+head][m][n] (64x64).
__global__ __launch_bounds__(256) void cb_kernel(
    const float* __restrict__ rpb, float* __restrict__ cbt)
{
    const int cls = blockIdx.x >> 3, head = blockIdx.x & 7;
    for (int e = threadIdx.x; e < 64 * 64; e += 256) {
        const int m = e >> 6, n = e & 63;
        float v;
        if (m >= 49 || n >= 49) v = -30000.0f;
        else {
            const int in_ = n / 7, jn = n - in_ * 7;
            const int im = m / 7, jm = m - im * 7;
            v = rpb[((in_ - im + 6) * 13 + (jn - jm + 6)) * 8 + head];
            const int hn = (cls & 2) ? 217 + in_ : in_;
            const int wn = (cls & 1) ? 49 + jn : jn;
            const int hm = (cls & 2) ? 217 + im : im;
            const int wm = (cls & 1) ? 49 + jm : jm;
            const int rn = (hn < 217 ? 0 : (hn < 221 ? 3 : 6)) + (wn < 49 ? 0 : (wn < 53 ? 1 : 2));
            const int rm = (hm < 217 ? 0 : (hm < 221 ? 3 : 6)) + (wm < 49 ? 0 : (wm < 53 ? 1 : 2));
            if (rn != rm) v -= 100.0f;
        }
        cbt[((long)blockIdx.x * 64 + m) * 64 + n] = v;
    }
}

// LN over C=256 fused with roll(-3,-3) + 7x7 window partition gather -> bf16.
// One WAVE per token (4 tokens/block).
__global__ __launch_bounds__(256) void ln1_window_kernel(
    const float* __restrict__ x1, const float* __restrict__ g,
    const float* __restrict__ b, __hip_bfloat16* __restrict__ out)
{
    const int wave = threadIdx.x >> 6, lane = threadIdx.x & 63;
    const int t = blockIdx.x * 4 + wave;
    const int bw = t / TPW, n = t - bw * TPW;
    const int bb = bw >> 8, wi = bw & 255;
    const int hb = wi >> 3, wb = wi & 7;
    const int i = n / 7, j = n - i * 7;
    int h0 = hb * 7 + i + 3; if (h0 >= GH) h0 -= GH;
    int w0 = wb * 7 + j + 3; if (w0 >= GW) w0 -= GW;
    const long src = ((long)(bb * GH + h0) * GW + w0) * CDIM + lane * 4;
    const float4 v = *(const float4*)(x1 + src);
    float s = v.x + v.y + v.z + v.w;
    s = wave_sum(s);
    const float mean = __shfl(s, 0) * (1.0f / 256.0f);
    const float4 d = { v.x - mean, v.y - mean, v.z - mean, v.w - mean };
    float s2 = d.x * d.x + d.y * d.y + d.z * d.z + d.w * d.w;
    s2 = wave_sum(s2);
    const float rstd = rsqrtf(__shfl(s2, 0) * (1.0f / 256.0f) + 1e-5f);
    const float4 g4 = *(const float4*)(g + lane * 4);
    const float4 b4 = *(const float4*)(b + lane * 4);
    short4 pk;
    { __bf16 h = to_bf16(d.x * rstd * g4.x + b4.x); pk.x = *(short*)&h; }
    { __bf16 h = to_bf16(d.y * rstd * g4.y + b4.y); pk.y = *(short*)&h; }
    { __bf16 h = to_bf16(d.z * rstd * g4.z + b4.z); pk.z = *(short*)&h; }
    { __bf16 h = to_bf16(d.w * rstd * g4.w + b4.w); pk.w = *(short*)&h; }
    *(short4*)((short*)out + (long)t * CDIM + lane * 4) = pk;
}

// Plain LN over C=256 -> bf16. One WAVE per token (4 tokens/block).
__global__ __launch_bounds__(256) void ln_kernel(
    const float* __restrict__ x, const float* __restrict__ g,
    const float* __restrict__ b, __hip_bfloat16* __restrict__ out)
{
    const int wave = threadIdx.x >> 6, lane = threadIdx.x & 63;
    const long t = (long)blockIdx.x * 4 + wave;
    const float4 v = *(const float4*)(x + t * CDIM + lane * 4);
    float s = v.x + v.y + v.z + v.w;
    s = wave_sum(s);
    const float mean = __shfl(s, 0) * (1.0f / 256.0f);
    const float4 d = { v.x - mean, v.y - mean, v.z - mean, v.w - mean };
    float s2 = d.x * d.x + d.y * d.y + d.z * d.z + d.w * d.w;
    s2 = wave_sum(s2);
    const float rstd = rsqrtf(__shfl(s2, 0) * (1.0f / 256.0f) + 1e-5f);
    const float4 g4 = *(const float4*)(g + lane * 4);
    const float4 b4 = *(const float4*)(b + lane * 4);
    short4 pk;
    { __bf16 h = to_bf16(d.x * rstd * g4.x + b4.x); pk.x = *(short*)&h; }
    { __bf16 h = to_bf16(d.y * rstd * g4.y + b4.y); pk.y = *(short*)&h; }
    { __bf16 h = to_bf16(d.z * rstd * g4.z + b4.z); pk.z = *(short*)&h; }
    { __bf16 h = to_bf16(d.w * rstd * g4.w + b4.w); pk.w = *(short*)&h; }
    *(short4*)((short*)out + t * CDIM + lane * 4) = pk;
}

// MFMA GEMM v6: 128x256 tile (full-N for fc2/proj), BK=32, 8 waves (512 thr),
// double-buffered LDS with issue-early prefetch, XCD-swizzled grid.
// Wave grid 2M x 4N; per-wave 64x64 output, acc[4][4] (64 VGPR) — identical
// per-wave structure to the proven 128x128 kernel. A-panel staged once per
// 256-wide col-tile (halves A redundancy and block count vs 128-wide).
// EPI: 0 = bias (bf16 out), 1 = bias+GELU (bf16 out), 2 = bias + fp32
// residual (fp32 out, in-place safe), 3 = proj+scatter.
template <int EPI, typename OutT>
__global__ __launch_bounds__(512) void gemm_mfma(
    const __hip_bfloat16* __restrict__ X, const __hip_bfloat16* __restrict__ W,
    const float* __restrict__ bias, OutT* __restrict__ Y,
    int M, int K, int N, const float* __restrict__ res, float* __restrict__ Y2)
{
    __shared__ __hip_bfloat16 As[2][128 * 32];   // 8 KB per buffer
    __shared__ __hip_bfloat16 Bs[2][256 * 32];   // 16 KB per buffer
    const int tid = threadIdx.x;
    const int wave = tid >> 6, lane = tid & 63;
    const int nwg = gridDim.x * gridDim.y;
    const int L = blockIdx.y * gridDim.x + blockIdx.x;
    const int cpx = nwg >> 3;
    const int orig = (L & 7) * cpx + (L >> 3);
    const int bxx = orig % gridDim.x;
    const int byy = orig / gridDim.x;
    const int bm = byy * 128, bn = bxx * 256;
    const int wm = (wave & 1) * 64, wn = (wave >> 1) * 64;
    const int m16 = lane & 15, quad = lane >> 4;
    const int srow = tid >> 2;          // 0..127
    const int scol = (tid & 3) * 8;     // bf16 elems

    // staging sources: thread tid covers A row srow and W rows srow, 128+srow
    const __hip_bfloat16* xrow  = X + (long)(bm + srow) * K + scol;
    const __hip_bfloat16* wrow0 = W + (long)(bn + srow) * K + scol;
    const __hip_bfloat16* wrow1 = W + (long)(bn + 128 + srow) * K + scol;
    const int wb1k = wave * 1024;       // wave-uniform LDS byte base

    f32x4 acc[4][4] = {};

    // prologue: stage K-tile 0 into buffer 0
    async_copy16(xrow,  (char*)As[0] + wb1k);
    async_copy16(wrow0, (char*)Bs[0] + wb1k);
    async_copy16(wrow1, (char*)Bs[0] + 8192 + wb1k);
    __syncthreads();

    int cur = 0;
    for (int k0 = 0; k0 < K; k0 += 32) {
        if (k0 + 32 < K) {
            const int nxt = cur ^ 1;
            async_copy16(xrow + k0 + 32,  (char*)As[nxt] + wb1k);
            async_copy16(wrow0 + k0 + 32, (char*)Bs[nxt] + wb1k);
            async_copy16(wrow1 + k0 + 32, (char*)Bs[nxt] + 8192 + wb1k);
        }
        bf16x8 af[4], bf[4];
#pragma unroll
        for (int i = 0; i < 4; ++i)
            af[i] = *(const bf16x8*)&As[cur][(wm + i * 16 + m16) * 32 + quad * 8];
#pragma unroll
        for (int j = 0; j < 4; ++j)
            bf[j] = *(const bf16x8*)&Bs[cur][(wn + j * 16 + m16) * 32 + quad * 8];
        // swapped operands: D = C^T layout -> lane owns 4 consecutive cols
#pragma unroll
        for (int i = 0; i < 4; ++i)
#pragma unroll
            for (int j = 0; j < 4; ++j)
                acc[i][j] = __builtin_amdgcn_mfma_f32_16x16x32_bf16(bf[j], af[i], acc[i][j], 0, 0, 0);
        __syncthreads();   // lgkm: our reads done; vmcnt: prefetch landed
        cur ^= 1;
    }

#pragma unroll
    for (int i = 0; i < 4; ++i) {
        const long row = bm + wm + i * 16 + m16;
        long drow = row;
        if (EPI == 3) {
            const unsigned t = (unsigned)row;
            const unsigned bw_ = t / 49u;
            const unsigned n_ = t - bw_ * 49u;
            const unsigned bb = bw_ >> 8, wi = bw_ & 255u;
            const unsigned hb = wi >> 3, wbl = wi & 7u;
            const unsigned ii = n_ / 7u, jj = n_ - ii * 7u;
            int h0 = hb * 7 + ii + 3; if (h0 >= GH) h0 -= GH;
            int w0 = wbl * 7 + jj + 3; if (w0 >= GW) w0 -= GW;
            drow = (long)bb * (GH * GW) + h0 * GW + w0;
        }
#pragma unroll
        for (int j = 0; j < 4; ++j) {
            const int col = bn + wn + j * 16 + quad * 4;
            const float4 b4 = *(const float4*)&bias[col];
            float v[4];
            v[0] = acc[i][j][0] + b4.x;
            v[1] = acc[i][j][1] + b4.y;
            v[2] = acc[i][j][2] + b4.z;
            v[3] = acc[i][j][3] + b4.w;
            if (EPI == 1) {
#pragma unroll
                for (int r = 0; r < 4; ++r)
                    v[r] = 0.5f * v[r] * (1.0f + erff(v[r] * 0.70710678118654752f));
            }
            if (EPI == 0 || EPI == 1) {
                short4 pk;
                { __bf16 h = to_bf16(v[0]); pk.x = *(short*)&h; }
                { __bf16 h = to_bf16(v[1]); pk.y = *(short*)&h; }
                { __bf16 h = to_bf16(v[2]); pk.z = *(short*)&h; }
                { __bf16 h = to_bf16(v[3]); pk.w = *(short*)&h; }
                *(short4*)((short*)Y + row * N + col) = pk;
            } else if (EPI == 2) {
                const float4 r4 = *(const float4*)(res + row * N + col);
                float4 o4 = { v[0] + r4.x, v[1] + r4.y, v[2] + r4.z, v[3] + r4.w };
                *(float4*)((float*)Y + row * N + col) = o4;
            } else if (EPI == 3) {
                const long a = drow * 256 + col;
                const float4 x4 = *(const float4*)(res + a);
                float4 y4 = { v[0], v[1], v[2], v[3] };
                *(float4*)(Y2 + a) = y4;
                float4 s4 = { v[0] + x4.x, v[1] + x4.y, v[2] + x4.z, v[3] + x4.w };
                *(float4*)((float*)Y + a) = s4;
            }
        }
    }
}

// MFMA attention: one wave per (window, head); block = 4 waves.
__global__ __launch_bounds__(256) void attn_mfma_kernel(
    const __hip_bfloat16* __restrict__ qkv,
    const float* __restrict__ cbt,
    __hip_bfloat16* __restrict__ yout)
{
    __shared__ __bf16 P[4][64][PLD];
    const int tid = threadIdx.x;
    const int wave = tid >> 6, lane = tid & 63;
    const int bw = blockIdx.x >> 1;
    const int head = (blockIdx.x & 1) * 4 + wave;
    const int m16 = lane & 15, quad = lane >> 4;
    const int wi = bw & 255;
    const int hb = wi >> 3, wb = wi & 7;
    const int cls = ((hb == 31) ? 2 : 0) + ((wb == 7) ? 1 : 0);

    const __bf16* qb = (const __bf16*)qkv + (long)bw * TPW * 768 + head * 32;

    bf16x8 qf[4], kf[4];
#pragma unroll
    for (int i = 0; i < 4; ++i) {
        const int n = i * 16 + m16;
        bf16x8 q = {}, k = {};
        if (n < TPW) {
            const __bf16* p = qb + (long)n * 768 + quad * 8;
            q = *(const bf16x8*)p;
            k = *(const bf16x8*)(p + 256);
        }
        qf[i] = q; kf[i] = k;
    }

    bf16x8 vf[2][2];
#pragma unroll
    for (int jt = 0; jt < 2; ++jt)
#pragma unroll
        for (int kt = 0; kt < 2; ++kt) {
            bf16x8 v = {};
#pragma unroll
            for (int j = 0; j < 8; ++j) {
                const int tok = kt * 32 + quad * 8 + j;
                if (tok < TPW) v[j] = qb[(long)tok * 768 + 512 + jt * 16 + m16];
            }
            vf[jt][kt] = v;
        }

    // S = Q K^T (C-layout: lane holds S[n=i*16+quad*4+r][m=j*16+m16])
    f32x4 s[4][4] = {};
#pragma unroll
    for (int i = 0; i < 4; ++i)
#pragma unroll
        for (int j = 0; j < 4; ++j)
            s[i][j] = __builtin_amdgcn_mfma_f32_16x16x32_bf16(qf[i], kf[j], s[i][j], 0, 0, 0);

    const float* cb = cbt + (long)(cls * 8 + head) * 64 * 64;   // [m][n]
#pragma unroll
    for (int j = 0; j < 4; ++j) {
        const int m = j * 16 + m16;
#pragma unroll
        for (int i = 0; i < 4; ++i) {
            const float4 c = *(const float4*)(cb + m * 64 + i * 16 + quad * 4);
            s[i][j][0] = s[i][j][0] * 0.17677669529663687f + c.x;
            s[i][j][1] = s[i][j][1] * 0.17677669529663687f + c.y;
            s[i][j][2] = s[i][j][2] * 0.17677669529663687f + c.z;
            s[i][j][3] = s[i][j][3] * 0.17677669529663687f + c.w;
        }
    }

    // row softmax; normalized P -> LDS
#pragma unroll
    for (int i = 0; i < 4; ++i) {
#pragma unroll
        for (int r = 0; r < 4; ++r) {
            float mx = fmaxf(fmaxf(s[i][0][r], s[i][1][r]), fmaxf(s[i][2][r], s[i][3][r]));
            mx = fmaxf(mx, __shfl_xor(mx, 1));
            mx = fmaxf(mx, __shfl_xor(mx, 2));
            mx = fmaxf(mx, __shfl_xor(mx, 4));
            mx = fmaxf(mx, __shfl_xor(mx, 8));
            float sum = 0.0f;
#pragma unroll
            for (int j = 0; j < 4; ++j) {
                const float e = __expf(s[i][j][r] - mx);
                s[i][j][r] = e;
                sum += e;
            }
            sum += __shfl_xor(sum, 1);
            sum += __shfl_xor(sum, 2);
            sum += __shfl_xor(sum, 4);
            sum += __shfl_xor(sum, 8);
            const float inv = 1.0f / sum;
#pragma unroll
            for (int j = 0; j < 4; ++j)
                P[wave][i * 16 + quad * 4 + r][j * 16 + m16] = to_bf16(s[i][j][r] * inv);
        }
    }

    // O = P V, swapped operands: lane holds O[tok=i*16+m16][d=jt*16+quad*4+r]
    f32x4 o[4][2] = {};
#pragma unroll
    for (int kt = 0; kt < 2; ++kt)
#pragma unroll
        for (int i = 0; i < 4; ++i) {
            const bf16x8 pf = *(const bf16x8*)&P[wave][i * 16 + m16][kt * 32 + quad * 8];
#pragma unroll
            for (int jt = 0; jt < 2; ++jt)
                o[i][jt] = __builtin_amdgcn_mfma_f32_16x16x32_bf16(vf[jt][kt], pf, o[i][jt], 0, 0, 0);
        }

#pragma unroll
    for (int i = 0; i < 4; ++i) {
        const int tok = i * 16 + m16;
        if (tok < TPW) {
#pragma unroll
            for (int jt = 0; jt < 2; ++jt) {
                short4 pk;
                { __bf16 h = to_bf16(o[i][jt][0]); pk.x = *(short*)&h; }
                { __bf16 h = to_bf16(o[i][jt][1]); pk.y = *(short*)&h; }
                { __bf16 h = to_bf16(o[i][jt][2]); pk.z = *(short*)&h; }
                { __bf16 h = to_bf16(o[i][jt][3]); pk.w = *(short*)&h; }
                *(short4*)((short*)yout + ((long)bw * TPW + tok) * CDIM + head * 32 + jt * 16 + quad * 4) = pk;
            }
        }
    }
}

extern "C" void kernel_launch(void* const* d_in, const int* in_sizes, int n_in,
                              void* d_out, int out_size, void* d_ws, size_t ws_size,
                              hipStream_t stream) {
    (void)in_sizes; (void)n_in; (void)out_size; (void)ws_size;
    const float* x1     = (const float*)d_in[0];
    const float* n1g    = (const float*)d_in[2];
    const float* n1b    = (const float*)d_in[3];
    const float* qkv_w  = (const float*)d_in[4];
    const float* qkv_b  = (const float*)d_in[5];
    const float* proj_w = (const float*)d_in[6];
    const float* proj_b = (const float*)d_in[7];
    const float* rpb    = (const float*)d_in[8];
    const float* n2g    = (const float*)d_in[9];
    const float* n2b    = (const float*)d_in[10];
    const float* fc1_w  = (const float*)d_in[11];
    const float* fc1_b  = (const float*)d_in[12];
    const float* fc2_w  = (const float*)d_in[13];
    const float* fc2_b  = (const float*)d_in[14];

    float* out_x1 = (float*)d_out;
    float* out_y  = out_x1 + (long)MTOK * CDIM;

    char* ws = (char*)d_ws;
    const size_t SZ_A   = (size_t)MTOK * CDIM * sizeof(__hip_bfloat16);   // 25.7 MB
    const size_t SZ_BIG = (size_t)MTOK * 1024 * sizeof(__hip_bfloat16);   // 102.8 MB
    __hip_bfloat16* A    = (__hip_bfloat16*)ws;            // ln1 out -> yattn -> ln2 out
    char*           BIG  = ws + SZ_A;                      // qkv bf16 -> h1 bf16
    __hip_bfloat16* qkvb = (__hip_bfloat16*)BIG;
    __hip_bfloat16* H1   = (__hip_bfloat16*)BIG;
    __hip_bfloat16* wB   = (__hip_bfloat16*)(ws + SZ_A + SZ_BIG);
    __hip_bfloat16* qkv_wb  = wB;               // 196608
    __hip_bfloat16* proj_wb = wB + 196608;      // 65536
    __hip_bfloat16* fc1_wb  = wB + 262144;      // 262144
    __hip_bfloat16* fc2_wb  = wB + 524288;      // 262144
    float* cbt = (float*)(wB + 786432);         // 512 KB

    // 0) weights -> bf16 (one launch); combined bias/mask table
    castall_kernel<<<3072, 256, 0, stream>>>(qkv_w, proj_w, fc1_w, fc2_w, wB);
    cb_kernel<<<32, 256, 0, stream>>>(rpb, cbt);
    // 1) LN1 + roll + window partition (bf16); one wave per token
    ln1_window_kernel<<<MTOK / 4, 256, 0, stream>>>(x1, n1g, n1b, A);
    // 2) QKV gemm -> bf16  (768 = 3 col-tiles of 256)
    gemm_mfma<0, __hip_bfloat16><<<dim3(768 / 256, MTOK / 128), 512, 0, stream>>>(
        A, qkv_wb, qkv_b, qkvb, MTOK, CDIM, 768, nullptr, nullptr);
    // 3) windowed attention (MFMA) -> bf16 (into A)
    attn_mfma_kernel<<<NWIN * 2, 256, 0, stream>>>(qkvb, cbt, A);
    // 4) proj + fused scatter: full-N single col-tile
    gemm_mfma<3, float><<<dim3(1, MTOK / 128), 512, 0, stream>>>(
        A, proj_wb, proj_b, out_x1, MTOK, CDIM, CDIM, x1, out_y);
    // 5) LN2 -> bf16 (into A); one wave per token
    ln_kernel<<<MTOK / 4, 256, 0, stream>>>(out_x1, n2g, n2b, A);
    // 6) fc1 + GELU -> bf16  (1024 = 4 col-tiles of 256)
    gemm_mfma<1, __hip_bfloat16><<<dim3(1024 / 256, MTOK / 128), 512, 0, stream>>>(
        A, fc1_wb, fc1_b, H1, MTOK, CDIM, 1024, nullptr, nullptr);
    // 7) fc2 + residual (in-place on out_x1); full-N single col-tile
    gemm_mfma<2, float><<<dim3(1, MTOK / 128), 512, 0, stream>>>(
        H1, fc2_wb, fc2_b, out_x1, MTOK, 1024, CDIM, out_x1, nullptr);
}